// Round 1
// baseline (5686.241 us; speedup 1.0000x reference)
//
#include <hip/hip_runtime.h>

// ---------------------------------------------------------------------------
// SAGEConvNet: 3x SAGEConv(mean) + ELU (after 1,2) + linear head.
// Round 0: correctness-first fp32 baseline.
//   deg      = segment_sum(1, dst)                 (atomic, once)
//   agg      = segment_sum(x[src], dst)            (atomic scatter per layer)
//   h        = (agg/max(deg,1)) @ Wl^T + b + x @ Wr^T   (fused tiled SGEMM)
// ---------------------------------------------------------------------------

static inline size_t ws_align(size_t x) { return (x + 511) & ~size_t(511); }

__global__ void count_deg_kernel(const int* __restrict__ dst, float* __restrict__ deg, int nE) {
    int e = blockIdx.x * blockDim.x + threadIdx.x;
    if (e < nE) atomicAdd(&deg[dst[e]], 1.0f);
}

// One edge handled by F/4 consecutive threads; lanes of a group read a
// contiguous float4 slice of the source row (coalesced within the row).
template<int F>
__global__ void scatter_kernel(const float* __restrict__ feat,
                               const int* __restrict__ srcArr,
                               const int* __restrict__ dstArr,
                               float* __restrict__ agg, int nE) {
    constexpr int C = F / 4;
    int gid = blockIdx.x * blockDim.x + threadIdx.x;
    int e = gid / C;
    int c = gid % C;
    if (e >= nE) return;
    int s = srcArr[e];
    int d = dstArr[e];
    const float4 v = *reinterpret_cast<const float4*>(feat + (size_t)s * F + c * 4);
    float* p = agg + (size_t)d * F + c * 4;
    atomicAdd(p + 0, v.x);
    atomicAdd(p + 1, v.y);
    atomicAdd(p + 2, v.z);
    atomicAdd(p + 3, v.w);
}

// Fused linear: out[n][j] = bias[j] + sum_k A[n][k] * W[j][k]
// where A = [mean | xin] (TWO=true, K=2F) or A = A1 (TWO=false, K=F).
// Block: 64 nodes x 64 outputs, 256 threads, 4x4 microtile per thread.
template<int F, bool TWO, bool DOELU, int NOUT>
__global__ void lin_kernel(const float* __restrict__ A1,   // agg (TWO) or plain input
                           const float* __restrict__ deg,  // used when TWO
                           const float* __restrict__ A2,   // root input (TWO)
                           const float* __restrict__ Wl,   // NOUT x F
                           const float* __restrict__ Wr,   // NOUT x F (TWO)
                           const float* __restrict__ bias, // NOUT
                           float* __restrict__ out, int nN) {
    constexpr int K = TWO ? 2 * F : F;
    constexpr int NCH = K / 32;

    __shared__ float As[64][36];   // +4 pad keeps float4 alignment, spreads banks
    __shared__ float Bs[32][64];

    const int t = threadIdx.x;
    const int block0 = blockIdx.x * 64;
    const int tm = (t >> 4) << 2;  // node sub-tile base (0..60)
    const int tn = (t & 15) << 2;  // output sub-tile base (0..60)

    float acc[4][4] = {};

    for (int ch = 0; ch < NCH; ++ch) {
        const int kg0 = ch * 32;
        // -------- stage A chunk (64 nodes x 32 k) --------
        {
            const bool isMean = TWO && (kg0 < F);
            const float* srcp;
            int koff;
            if (TWO) {
                if (isMean) { srcp = A1; koff = kg0; }
                else        { srcp = A2; koff = kg0 - F; }
            } else { srcp = A1; koff = kg0; }
            const int kk = (t & 7) * 4;
#pragma unroll
            for (int r = 0; r < 2; ++r) {
                const int n = (t >> 3) + r * 32;
                const int node = block0 + n;
                float4 v = make_float4(0.f, 0.f, 0.f, 0.f);
                if (node < nN) {
                    v = *reinterpret_cast<const float4*>(srcp + (size_t)node * F + koff + kk);
                    if (isMean) {
                        const float sc = 1.0f / fmaxf(deg[node], 1.0f);
                        v.x *= sc; v.y *= sc; v.z *= sc; v.w *= sc;
                    }
                }
                *reinterpret_cast<float4*>(&As[n][kk]) = v;
            }
        }
        // -------- stage B chunk (32 k x 64 outputs, transposed) --------
        {
            const float* wp;
            int wk;
            if (TWO && kg0 >= F) { wp = Wr; wk = kg0 - F; }
            else                 { wp = Wl; wk = kg0; }
            const int j = t & 63;
#pragma unroll
            for (int p = 0; p < 8; ++p) {
                const int kk = (t >> 6) + p * 4;
                Bs[kk][j] = (j < NOUT) ? wp[(size_t)j * F + wk + kk] : 0.0f;
            }
        }
        __syncthreads();
        // -------- compute --------
#pragma unroll
        for (int kk = 0; kk < 32; ++kk) {
            const float a0 = As[tm + 0][kk];
            const float a1 = As[tm + 1][kk];
            const float a2 = As[tm + 2][kk];
            const float a3 = As[tm + 3][kk];
            const float4 bv = *reinterpret_cast<const float4*>(&Bs[kk][tn]);
            acc[0][0] += a0 * bv.x; acc[0][1] += a0 * bv.y; acc[0][2] += a0 * bv.z; acc[0][3] += a0 * bv.w;
            acc[1][0] += a1 * bv.x; acc[1][1] += a1 * bv.y; acc[1][2] += a1 * bv.z; acc[1][3] += a1 * bv.w;
            acc[2][0] += a2 * bv.x; acc[2][1] += a2 * bv.y; acc[2][2] += a2 * bv.z; acc[2][3] += a2 * bv.w;
            acc[3][0] += a3 * bv.x; acc[3][1] += a3 * bv.y; acc[3][2] += a3 * bv.z; acc[3][3] += a3 * bv.w;
        }
        __syncthreads();
    }

    // -------- epilogue --------
#pragma unroll
    for (int i = 0; i < 4; ++i) {
        const int node = block0 + tm + i;
        if (node >= nN) continue;
        if constexpr (NOUT == 64) {
            float4 st;
            float* pv = &st.x;
#pragma unroll
            for (int j = 0; j < 4; ++j) {
                float v = acc[i][j] + bias[tn + j];
                if (DOELU) v = v > 0.0f ? v : expm1f(v);
                pv[j] = v;
            }
            *reinterpret_cast<float4*>(out + (size_t)node * 64 + tn) = st;
        } else {
#pragma unroll
            for (int j = 0; j < 4; ++j) {
                const int col = tn + j;
                if (col < NOUT) {
                    float v = acc[i][j] + bias[col];
                    if (DOELU) v = v > 0.0f ? v : expm1f(v);
                    out[(size_t)node * NOUT + col] = v;
                }
            }
        }
    }
}

extern "C" void kernel_launch(void* const* d_in, const int* in_sizes, int n_in,
                              void* d_out, int out_size, void* d_ws, size_t ws_size,
                              hipStream_t stream) {
    const float* x    = (const float*)d_in[0];
    const int*   ei   = (const int*)d_in[1];
    const float* W1l  = (const float*)d_in[2];
    const float* b1   = (const float*)d_in[3];
    const float* W1r  = (const float*)d_in[4];
    const float* W2l  = (const float*)d_in[5];
    const float* b2   = (const float*)d_in[6];
    const float* W2r  = (const float*)d_in[7];
    const float* W3l  = (const float*)d_in[8];
    const float* b3   = (const float*)d_in[9];
    const float* W3r  = (const float*)d_in[10];
    const float* Wout = (const float*)d_in[11];
    const float* bout = (const float*)d_in[12];

    const int N = in_sizes[0] / 128;   // 100000
    const int E = in_sizes[1] / 2;     // 1600000
    const int* src  = ei;
    const int* dstA = ei + E;

    char* ws = (char*)d_ws;
    size_t o = 0;
    float* deg = (float*)(ws + o); o += ws_align((size_t)N * 4);
    float* agg = (float*)(ws + o); o += ws_align((size_t)N * 128 * 4);
    float* h1  = (float*)(ws + o); o += ws_align((size_t)N * 64 * 4);
    float* h2  = (float*)(ws + o); o += ws_align((size_t)N * 64 * 4);
    float* h3  = h1;  // layer-3 output reuses h1's space
    float* outp = (float*)d_out;

    const int linGrid = (N + 63) / 64;

    // degree (shared by all layers)
    hipMemsetAsync(deg, 0, (size_t)N * 4, stream);
    count_deg_kernel<<<(E + 255) / 256, 256, 0, stream>>>(dstA, deg, E);

    // ---- layer 1 (F=128 -> 64, ELU) ----
    hipMemsetAsync(agg, 0, (size_t)N * 128 * 4, stream);
    {
        const int tot = E * 32;  // E * F/4 threads
        scatter_kernel<128><<<(tot + 255) / 256, 256, 0, stream>>>(x, src, dstA, agg, E);
        lin_kernel<128, true, true, 64><<<linGrid, 256, 0, stream>>>(
            agg, deg, x, W1l, W1r, b1, h1, N);
    }

    // ---- layer 2 (64 -> 64, ELU) ----
    hipMemsetAsync(agg, 0, (size_t)N * 64 * 4, stream);
    {
        const int tot = E * 16;
        scatter_kernel<64><<<(tot + 255) / 256, 256, 0, stream>>>(h1, src, dstA, agg, E);
        lin_kernel<64, true, true, 64><<<linGrid, 256, 0, stream>>>(
            agg, deg, h1, W2l, W2r, b2, h2, N);
    }

    // ---- layer 3 (64 -> 64, no ELU) ----
    hipMemsetAsync(agg, 0, (size_t)N * 64 * 4, stream);
    {
        const int tot = E * 16;
        scatter_kernel<64><<<(tot + 255) / 256, 256, 0, stream>>>(h2, src, dstA, agg, E);
        lin_kernel<64, true, false, 64><<<linGrid, 256, 0, stream>>>(
            agg, deg, h2, W3l, W3r, b3, h3, N);
    }

    // ---- output head (64 -> 40) ----
    lin_kernel<64, false, false, 40><<<linGrid, 256, 0, stream>>>(
        h3, nullptr, nullptr, Wout, nullptr, bout, outp, N);
}

// Round 2
// 599.170 us; speedup vs baseline: 9.4902x; 9.4902x over previous
//
#include <hip/hip_runtime.h>

// ---------------------------------------------------------------------------
// SAGEConvNet round 1: CSR gather-mean (no float atomics) + project-first.
//   per call: build CSR (deg count -> scan -> fill)          [int atomics only]
//   per layer: xl = h@Wl^T ; xr = h@Wr^T + b   (dual GEMM, one A staging)
//              h' = ELU( gather_mean(xl) + xr )              [wave per node]
//   head: h3 @ Wout^T + bout
// ---------------------------------------------------------------------------

static inline size_t ws_align(size_t x) { return (x + 511) & ~size_t(511); }

// ----------------------------- CSR build -----------------------------------

__global__ void count_deg_int(const int* __restrict__ dst, int* __restrict__ degi, int nE) {
    int e = blockIdx.x * blockDim.x + threadIdx.x;
    if (e < nE) atomicAdd(&degi[dst[e]], 1);
}

// chunk of 1024 per block (256 threads x 4 sequential)
__global__ void block_sum_kernel(const int* __restrict__ degi, int* __restrict__ partial, int N) {
    __shared__ int sdata[256];
    const int t = threadIdx.x;
    const int base = blockIdx.x * 1024 + t * 4;
    int s = 0;
#pragma unroll
    for (int q = 0; q < 4; ++q) {
        const int i = base + q;
        if (i < N) s += degi[i];
    }
    sdata[t] = s;
    __syncthreads();
    for (int off = 128; off > 0; off >>= 1) {
        if (t < off) sdata[t] += sdata[t + off];
        __syncthreads();
    }
    if (t == 0) partial[blockIdx.x] = sdata[0];
}

__global__ void scan_partial_kernel(int* __restrict__ partial, int nb) {
    if (threadIdx.x == 0 && blockIdx.x == 0) {
        int run = 0;
        for (int i = 0; i < nb; ++i) { int v = partial[i]; partial[i] = run; run += v; }
    }
}

__global__ void block_scan_kernel(const int* __restrict__ degi, const int* __restrict__ partial,
                                  int* __restrict__ rowptr, int N, int E) {
    __shared__ int sdata[256];
    const int t = threadIdx.x;
    const int base = blockIdx.x * 1024 + t * 4;
    int v[4];
    int tsum = 0;
#pragma unroll
    for (int q = 0; q < 4; ++q) {
        const int i = base + q;
        v[q] = (i < N) ? degi[i] : 0;
        tsum += v[q];
    }
    sdata[t] = tsum;
    __syncthreads();
    // inclusive Hillis-Steele scan over 256 thread sums
    for (int off = 1; off < 256; off <<= 1) {
        int add = (t >= off) ? sdata[t - off] : 0;
        __syncthreads();
        sdata[t] += add;
        __syncthreads();
    }
    int run = partial[blockIdx.x] + sdata[t] - tsum;  // exclusive prefix for this thread
#pragma unroll
    for (int q = 0; q < 4; ++q) {
        const int i = base + q;
        if (i < N) { rowptr[i] = run; run += v[q]; }
    }
    if (blockIdx.x == 0 && t == 0) rowptr[N] = E;
}

__global__ void fill_csr_kernel(const int* __restrict__ src, const int* __restrict__ dst,
                                int* __restrict__ cursor, int* __restrict__ csr, int nE) {
    int e = blockIdx.x * blockDim.x + threadIdx.x;
    if (e < nE) {
        const int pos = atomicAdd(&cursor[dst[e]], 1);
        csr[pos] = src[e];
    }
}

// ----------------------------- GEMMs ---------------------------------------

// Dual projection: outl = A@Wl^T ; outr = A@Wr^T + bias.  64x64 block tile,
// 256 threads, 4x4 microtile per thread per output.
template<int F>
__global__ void proj2_kernel(const float* __restrict__ A,
                             const float* __restrict__ Wl,
                             const float* __restrict__ Wr,
                             const float* __restrict__ bias,
                             float* __restrict__ outl, float* __restrict__ outr, int nN) {
    constexpr int NCH = F / 32;

    __shared__ float As[64][36];
    __shared__ float Bl[32][64];
    __shared__ float Br[32][64];

    const int t = threadIdx.x;
    const int block0 = blockIdx.x * 64;
    const int tm = (t >> 4) << 2;
    const int tn = (t & 15) << 2;

    float accl[4][4] = {};
    float accr[4][4] = {};

    for (int ch = 0; ch < NCH; ++ch) {
        const int kg0 = ch * 32;
        // stage A chunk (64 nodes x 32 k)
        {
            const int kk = (t & 7) * 4;
#pragma unroll
            for (int r = 0; r < 2; ++r) {
                const int n = (t >> 3) + r * 32;
                const int node = block0 + n;
                float4 v = make_float4(0.f, 0.f, 0.f, 0.f);
                if (node < nN)
                    v = *reinterpret_cast<const float4*>(A + (size_t)node * F + kg0 + kk);
                *reinterpret_cast<float4*>(&As[n][kk]) = v;
            }
        }
        // stage both B chunks (32 k x 64 outs, transposed)
        {
            const int j = t & 63;
#pragma unroll
            for (int p = 0; p < 8; ++p) {
                const int kk = (t >> 6) + p * 4;
                Bl[kk][j] = Wl[(size_t)j * F + kg0 + kk];
                Br[kk][j] = Wr[(size_t)j * F + kg0 + kk];
            }
        }
        __syncthreads();
#pragma unroll
        for (int kk = 0; kk < 32; ++kk) {
            const float a0 = As[tm + 0][kk];
            const float a1 = As[tm + 1][kk];
            const float a2 = As[tm + 2][kk];
            const float a3 = As[tm + 3][kk];
            const float4 bl = *reinterpret_cast<const float4*>(&Bl[kk][tn]);
            const float4 br = *reinterpret_cast<const float4*>(&Br[kk][tn]);
            accl[0][0] += a0 * bl.x; accl[0][1] += a0 * bl.y; accl[0][2] += a0 * bl.z; accl[0][3] += a0 * bl.w;
            accl[1][0] += a1 * bl.x; accl[1][1] += a1 * bl.y; accl[1][2] += a1 * bl.z; accl[1][3] += a1 * bl.w;
            accl[2][0] += a2 * bl.x; accl[2][1] += a2 * bl.y; accl[2][2] += a2 * bl.z; accl[2][3] += a2 * bl.w;
            accl[3][0] += a3 * bl.x; accl[3][1] += a3 * bl.y; accl[3][2] += a3 * bl.z; accl[3][3] += a3 * bl.w;
            accr[0][0] += a0 * br.x; accr[0][1] += a0 * br.y; accr[0][2] += a0 * br.z; accr[0][3] += a0 * br.w;
            accr[1][0] += a1 * br.x; accr[1][1] += a1 * br.y; accr[1][2] += a1 * br.z; accr[1][3] += a1 * br.w;
            accr[2][0] += a2 * br.x; accr[2][1] += a2 * br.y; accr[2][2] += a2 * br.z; accr[2][3] += a2 * br.w;
            accr[3][0] += a3 * br.x; accr[3][1] += a3 * br.y; accr[3][2] += a3 * br.z; accr[3][3] += a3 * br.w;
        }
        __syncthreads();
    }

#pragma unroll
    for (int i = 0; i < 4; ++i) {
        const int node = block0 + tm + i;
        if (node >= nN) continue;
        float4 sl, sr;
        float* pl = &sl.x;
        float* pr = &sr.x;
#pragma unroll
        for (int j = 0; j < 4; ++j) {
            pl[j] = accl[i][j];
            pr[j] = accr[i][j] + bias[tn + j];
        }
        *reinterpret_cast<float4*>(outl + (size_t)node * 64 + tn) = sl;
        *reinterpret_cast<float4*>(outr + (size_t)node * 64 + tn) = sr;
    }
}

// Head: out = A@W^T + bias, generic NOUT (<=64), K=F.
template<int F, int NOUT>
__global__ void head_kernel(const float* __restrict__ A,
                            const float* __restrict__ W,
                            const float* __restrict__ bias,
                            float* __restrict__ out, int nN) {
    constexpr int NCH = F / 32;
    __shared__ float As[64][36];
    __shared__ float Bs[32][64];

    const int t = threadIdx.x;
    const int block0 = blockIdx.x * 64;
    const int tm = (t >> 4) << 2;
    const int tn = (t & 15) << 2;

    float acc[4][4] = {};

    for (int ch = 0; ch < NCH; ++ch) {
        const int kg0 = ch * 32;
        {
            const int kk = (t & 7) * 4;
#pragma unroll
            for (int r = 0; r < 2; ++r) {
                const int n = (t >> 3) + r * 32;
                const int node = block0 + n;
                float4 v = make_float4(0.f, 0.f, 0.f, 0.f);
                if (node < nN)
                    v = *reinterpret_cast<const float4*>(A + (size_t)node * F + kg0 + kk);
                *reinterpret_cast<float4*>(&As[n][kk]) = v;
            }
        }
        {
            const int j = t & 63;
#pragma unroll
            for (int p = 0; p < 8; ++p) {
                const int kk = (t >> 6) + p * 4;
                Bs[kk][j] = (j < NOUT) ? W[(size_t)j * F + kg0 + kk] : 0.0f;
            }
        }
        __syncthreads();
#pragma unroll
        for (int kk = 0; kk < 32; ++kk) {
            const float a0 = As[tm + 0][kk];
            const float a1 = As[tm + 1][kk];
            const float a2 = As[tm + 2][kk];
            const float a3 = As[tm + 3][kk];
            const float4 bv = *reinterpret_cast<const float4*>(&Bs[kk][tn]);
            acc[0][0] += a0 * bv.x; acc[0][1] += a0 * bv.y; acc[0][2] += a0 * bv.z; acc[0][3] += a0 * bv.w;
            acc[1][0] += a1 * bv.x; acc[1][1] += a1 * bv.y; acc[1][2] += a1 * bv.z; acc[1][3] += a1 * bv.w;
            acc[2][0] += a2 * bv.x; acc[2][1] += a2 * bv.y; acc[2][2] += a2 * bv.z; acc[2][3] += a2 * bv.w;
            acc[3][0] += a3 * bv.x; acc[3][1] += a3 * bv.y; acc[3][2] += a3 * bv.z; acc[3][3] += a3 * bv.w;
        }
        __syncthreads();
    }

#pragma unroll
    for (int i = 0; i < 4; ++i) {
        const int node = block0 + tm + i;
        if (node >= nN) continue;
#pragma unroll
        for (int j = 0; j < 4; ++j) {
            const int col = tn + j;
            if (col < NOUT)
                out[(size_t)node * NOUT + col] = acc[i][j] + bias[col];
        }
    }
}

// ----------------------------- gather-mean ----------------------------------

// one wave per node; lane holds one of 64 feature components.
template<bool DOELU>
__global__ void gather_kernel(const float* __restrict__ xl, const float* __restrict__ xr,
                              const int* __restrict__ rowptr, const int* __restrict__ csr,
                              float* __restrict__ out, int nN) {
    const int node = blockIdx.x * (blockDim.x >> 6) + (threadIdx.x >> 6);
    if (node >= nN) return;
    const int lane = threadIdx.x & 63;
    const int b = rowptr[node];
    const int e = rowptr[node + 1];
    float acc = 0.f;
    int i = b;
    for (; i + 4 <= e; i += 4) {
        const int s0 = csr[i + 0];
        const int s1 = csr[i + 1];
        const int s2 = csr[i + 2];
        const int s3 = csr[i + 3];
        const float v0 = xl[(size_t)s0 * 64 + lane];
        const float v1 = xl[(size_t)s1 * 64 + lane];
        const float v2 = xl[(size_t)s2 * 64 + lane];
        const float v3 = xl[(size_t)s3 * 64 + lane];
        acc += v0 + v1 + v2 + v3;
    }
    for (; i < e; ++i) acc += xl[(size_t)csr[i] * 64 + lane];
    const float d = (float)(e - b);
    float v = acc / fmaxf(d, 1.0f) + xr[(size_t)node * 64 + lane];
    if (DOELU) v = v > 0.f ? v : expm1f(v);
    out[(size_t)node * 64 + lane] = v;
}

// ----------------------------- launch ---------------------------------------

extern "C" void kernel_launch(void* const* d_in, const int* in_sizes, int n_in,
                              void* d_out, int out_size, void* d_ws, size_t ws_size,
                              hipStream_t stream) {
    const float* x    = (const float*)d_in[0];
    const int*   ei   = (const int*)d_in[1];
    const float* W1l  = (const float*)d_in[2];
    const float* b1   = (const float*)d_in[3];
    const float* W1r  = (const float*)d_in[4];
    const float* W2l  = (const float*)d_in[5];
    const float* b2   = (const float*)d_in[6];
    const float* W2r  = (const float*)d_in[7];
    const float* W3l  = (const float*)d_in[8];
    const float* b3   = (const float*)d_in[9];
    const float* W3r  = (const float*)d_in[10];
    const float* Wout = (const float*)d_in[11];
    const float* bout = (const float*)d_in[12];

    const int N = in_sizes[0] / 128;   // 100000
    const int E = in_sizes[1] / 2;     // 1600000
    const int* src  = ei;
    const int* dstA = ei + E;

    char* ws = (char*)d_ws;
    size_t o = 0;
    int* degi    = (int*)(ws + o); o += ws_align((size_t)N * 4);
    int* partial = (int*)(ws + o); o += ws_align(4096);
    int* rowptr  = (int*)(ws + o); o += ws_align((size_t)(N + 1) * 4);
    int* cursor  = (int*)(ws + o); o += ws_align((size_t)N * 4);
    int* csr     = (int*)(ws + o); o += ws_align((size_t)E * 4);
    float* xl    = (float*)(ws + o); o += ws_align((size_t)N * 64 * 4);
    float* xr    = (float*)(ws + o); o += ws_align((size_t)N * 64 * 4);
    float* hA    = (float*)(ws + o); o += ws_align((size_t)N * 64 * 4);
    float* hB    = (float*)(ws + o); o += ws_align((size_t)N * 64 * 4);
    float* outp  = (float*)d_out;

    const int nb = (N + 1023) / 1024;
    const int gemmGrid = (N + 63) / 64;
    const int gatherGrid = (N + 3) / 4;

    // ---- CSR build ----
    hipMemsetAsync(degi, 0, (size_t)N * 4, stream);
    count_deg_int<<<(E + 255) / 256, 256, 0, stream>>>(dstA, degi, E);
    block_sum_kernel<<<nb, 256, 0, stream>>>(degi, partial, N);
    scan_partial_kernel<<<1, 64, 0, stream>>>(partial, nb);
    block_scan_kernel<<<nb, 256, 0, stream>>>(degi, partial, rowptr, N, E);
    hipMemcpyAsync(cursor, rowptr, (size_t)N * 4, hipMemcpyDeviceToDevice, stream);
    fill_csr_kernel<<<(E + 255) / 256, 256, 0, stream>>>(src, dstA, cursor, csr, E);

    // ---- layer 1 (128 -> 64, ELU) ----
    proj2_kernel<128><<<gemmGrid, 256, 0, stream>>>(x, W1l, W1r, b1, xl, xr, N);
    gather_kernel<true><<<gatherGrid, 256, 0, stream>>>(xl, xr, rowptr, csr, hA, N);

    // ---- layer 2 (64 -> 64, ELU) ----
    proj2_kernel<64><<<gemmGrid, 256, 0, stream>>>(hA, W2l, W2r, b2, xl, xr, N);
    gather_kernel<true><<<gatherGrid, 256, 0, stream>>>(xl, xr, rowptr, csr, hB, N);

    // ---- layer 3 (64 -> 64, no ELU) ----
    proj2_kernel<64><<<gemmGrid, 256, 0, stream>>>(hB, W3l, W3r, b3, xl, xr, N);
    gather_kernel<false><<<gatherGrid, 256, 0, stream>>>(xl, xr, rowptr, csr, hA, N);

    // ---- head (64 -> 40) ----
    head_kernel<64, 40><<<gemmGrid, 256, 0, stream>>>(hA, Wout, bout, outp, N);
}

// Round 4
// 529.807 us; speedup vs baseline: 10.7327x; 1.1309x over previous
//
#include <hip/hip_runtime.h>

// ---------------------------------------------------------------------------
// SAGEConvNet round 3: R2 (MFMA proj + bf16 gather) + hardening:
//   - no hipMemsetAsync (explicit zero kernel)
//   - range guards on all CSR-path indexed accesses (corruption containment)
// ---------------------------------------------------------------------------

static inline size_t ws_align(size_t x) { return (x + 511) & ~size_t(511); }

using frag_ab = __attribute__((ext_vector_type(8))) short;   // 8 bf16
using f32x4   = __attribute__((ext_vector_type(4))) float;   // 4 fp32 acc

__device__ inline short f2bf(float f) {            // RNE fp32 -> bf16
    unsigned u = __builtin_bit_cast(unsigned, f);
    u += 0x7fff + ((u >> 16) & 1);
    return (short)(u >> 16);
}
__device__ inline float b2f(unsigned short h) {
    unsigned u = ((unsigned)h) << 16;
    return __builtin_bit_cast(float, u);
}

// ----------------------------- utility --------------------------------------

__global__ void zero_kernel(int* __restrict__ p, int n) {
    int i = blockIdx.x * blockDim.x + threadIdx.x;
    if (i < n) p[i] = 0;
}

// ----------------------------- CSR build -----------------------------------

__global__ void count_deg_int(const int* __restrict__ dst, int* __restrict__ degi,
                              int nE, int nN) {
    int e = blockIdx.x * blockDim.x + threadIdx.x;
    if (e < nE) {
        const unsigned d = (unsigned)dst[e];
        if (d < (unsigned)nN) atomicAdd(&degi[d], 1);
    }
}

__global__ void block_sum_kernel(const int* __restrict__ degi, int* __restrict__ partial, int N) {
    __shared__ int sdata[256];
    const int t = threadIdx.x;
    const int base = blockIdx.x * 1024 + t * 4;
    int s = 0;
#pragma unroll
    for (int q = 0; q < 4; ++q) {
        const int i = base + q;
        if (i < N) s += degi[i];
    }
    sdata[t] = s;
    __syncthreads();
    for (int off = 128; off > 0; off >>= 1) {
        if (t < off) sdata[t] += sdata[t + off];
        __syncthreads();
    }
    if (t == 0) partial[blockIdx.x] = sdata[0];
}

__global__ void scan_partial_kernel(int* __restrict__ partial, int nb) {
    if (threadIdx.x == 0 && blockIdx.x == 0) {
        int run = 0;
        for (int i = 0; i < nb; ++i) { int v = partial[i]; partial[i] = run; run += v; }
    }
}

__global__ void block_scan_kernel(const int* __restrict__ degi, const int* __restrict__ partial,
                                  int* __restrict__ rowptr, int* __restrict__ cursor,
                                  int N, int E) {
    __shared__ int sdata[256];
    const int t = threadIdx.x;
    const int base = blockIdx.x * 1024 + t * 4;
    int v[4];
    int tsum = 0;
#pragma unroll
    for (int q = 0; q < 4; ++q) {
        const int i = base + q;
        v[q] = (i < N) ? degi[i] : 0;
        tsum += v[q];
    }
    sdata[t] = tsum;
    __syncthreads();
    for (int off = 1; off < 256; off <<= 1) {
        int add = (t >= off) ? sdata[t - off] : 0;
        __syncthreads();
        sdata[t] += add;
        __syncthreads();
    }
    int run = partial[blockIdx.x] + sdata[t] - tsum;
#pragma unroll
    for (int q = 0; q < 4; ++q) {
        const int i = base + q;
        if (i < N) { rowptr[i] = run; cursor[i] = run; run += v[q]; }
    }
    if (blockIdx.x == 0 && t == 0) rowptr[N] = E;
}

__global__ void fill_csr_kernel(const int* __restrict__ src, const int* __restrict__ dst,
                                int* __restrict__ cursor, int* __restrict__ csr,
                                int nE, int nN) {
    int e = blockIdx.x * blockDim.x + threadIdx.x;
    if (e < nE) {
        const unsigned d = (unsigned)dst[e];
        if (d < (unsigned)nN) {
            const int pos = atomicAdd(&cursor[d], 1);
            if ((unsigned)pos < (unsigned)nE) csr[pos] = src[e];   // contained
        }
    }
}

// --------------------- dual projection via bf16 MFMA -------------------------
// Block = 4 waves; each wave owns a 32(M)x64(N) strip: 2 m-frags x 4 n-frags of
// 16x16x32. A frag: lane reads A[m+(l&15)][k0+(l>>4)*8 .. +7]. W frags re-read
// per k-step (L2-hot). C/D layout: col=lane&15, row=(lane>>4)*4+reg.
template<int F, bool AF32>
__global__ void proj2_mfma(const void* __restrict__ Aptr,
                           const float* __restrict__ Wl,
                           const float* __restrict__ Wr,
                           const float* __restrict__ bias,
                           unsigned short* __restrict__ xl,  // bf16 [N][64]
                           float* __restrict__ xr,           // fp32 [N][64]
                           int nN) {
    const int t    = threadIdx.x;
    const int wave = t >> 6;
    const int lane = t & 63;
    const int lg   = lane >> 4;   // k-group (0..3)
    const int lr   = lane & 15;   // row (A) / col (B,C)
    const int mbase = blockIdx.x * 128 + wave * 32;

    const float*          Af = (const float*)Aptr;
    const unsigned short* Ab = (const unsigned short*)Aptr;

    f32x4 accl[2][4] = {};
    f32x4 accr[2][4] = {};

#pragma unroll
    for (int ks = 0; ks < F / 32; ++ks) {
        const int k0 = ks * 32 + lg * 8;
        frag_ab afr[2];
#pragma unroll
        for (int mf = 0; mf < 2; ++mf) {
            int row = mbase + mf * 16 + lr;
            if (row >= nN) row = nN - 1;           // clamp; tail rows masked at store
            if constexpr (AF32) {
                const float4 f0 = *reinterpret_cast<const float4*>(Af + (size_t)row * F + k0);
                const float4 f1 = *reinterpret_cast<const float4*>(Af + (size_t)row * F + k0 + 4);
                frag_ab a;
                a[0] = f2bf(f0.x); a[1] = f2bf(f0.y); a[2] = f2bf(f0.z); a[3] = f2bf(f0.w);
                a[4] = f2bf(f1.x); a[5] = f2bf(f1.y); a[6] = f2bf(f1.z); a[7] = f2bf(f1.w);
                afr[mf] = a;
            } else {
                afr[mf] = *reinterpret_cast<const frag_ab*>(Ab + (size_t)row * F + k0);
            }
        }
#pragma unroll
        for (int nf = 0; nf < 4; ++nf) {
            const int col = nf * 16 + lr;
            const float4 l0 = *reinterpret_cast<const float4*>(Wl + (size_t)col * F + k0);
            const float4 l1 = *reinterpret_cast<const float4*>(Wl + (size_t)col * F + k0 + 4);
            const float4 r0 = *reinterpret_cast<const float4*>(Wr + (size_t)col * F + k0);
            const float4 r1 = *reinterpret_cast<const float4*>(Wr + (size_t)col * F + k0 + 4);
            frag_ab bl, br;
            bl[0] = f2bf(l0.x); bl[1] = f2bf(l0.y); bl[2] = f2bf(l0.z); bl[3] = f2bf(l0.w);
            bl[4] = f2bf(l1.x); bl[5] = f2bf(l1.y); bl[6] = f2bf(l1.z); bl[7] = f2bf(l1.w);
            br[0] = f2bf(r0.x); br[1] = f2bf(r0.y); br[2] = f2bf(r0.z); br[3] = f2bf(r0.w);
            br[4] = f2bf(r1.x); br[5] = f2bf(r1.y); br[6] = f2bf(r1.z); br[7] = f2bf(r1.w);
            accl[0][nf] = __builtin_amdgcn_mfma_f32_16x16x32_bf16(afr[0], bl, accl[0][nf], 0, 0, 0);
            accl[1][nf] = __builtin_amdgcn_mfma_f32_16x16x32_bf16(afr[1], bl, accl[1][nf], 0, 0, 0);
            accr[0][nf] = __builtin_amdgcn_mfma_f32_16x16x32_bf16(afr[0], br, accr[0][nf], 0, 0, 0);
            accr[1][nf] = __builtin_amdgcn_mfma_f32_16x16x32_bf16(afr[1], br, accr[1][nf], 0, 0, 0);
        }
    }

#pragma unroll
    for (int mf = 0; mf < 2; ++mf) {
#pragma unroll
        for (int nf = 0; nf < 4; ++nf) {
            const int col = nf * 16 + lr;
            const float bv = bias[col];
#pragma unroll
            for (int j = 0; j < 4; ++j) {
                const int row = mbase + mf * 16 + lg * 4 + j;
                if (row < nN) {
                    xl[(size_t)row * 64 + col] = (unsigned short)f2bf(accl[mf][nf][j]);
                    xr[(size_t)row * 64 + col] = accr[mf][nf][j] + bv;
                }
            }
        }
    }
}

// ----------------------------- gather-mean ----------------------------------
// one wave per node; lane = feature. xl bf16 (128B/row), xr fp32 root path.
template<bool DOELU, bool OUTBF>
__global__ void gather_kernel(const unsigned short* __restrict__ xl,
                              const float* __restrict__ xr,
                              const int* __restrict__ rowptr, const int* __restrict__ csr,
                              void* __restrict__ outp, int nN, int nE) {
    const int node = blockIdx.x * (blockDim.x >> 6) + (threadIdx.x >> 6);
    if (node >= nN) return;
    const int lane = threadIdx.x & 63;
    int b = rowptr[node];
    int e = rowptr[node + 1];
    // containment clamps (no-ops when CSR is healthy)
    b = max(0, min(b, nE));
    e = max(b, min(e, nE));
    const float d = (float)(e - b);
    float acc = 0.f;
    int i = b;
    for (; i + 4 <= e; i += 4) {
        const unsigned s0 = (unsigned)csr[i + 0];
        const unsigned s1 = (unsigned)csr[i + 1];
        const unsigned s2 = (unsigned)csr[i + 2];
        const unsigned s3 = (unsigned)csr[i + 3];
        acc += b2f(xl[(size_t)s0 * 64 + lane]) + b2f(xl[(size_t)s1 * 64 + lane])
             + b2f(xl[(size_t)s2 * 64 + lane]) + b2f(xl[(size_t)s3 * 64 + lane]);
    }
    for (; i < e; ++i) acc += b2f(xl[(size_t)(unsigned)csr[i] * 64 + lane]);
    float v = acc / fmaxf(d, 1.0f) + xr[(size_t)node * 64 + lane];
    if (DOELU) v = v > 0.f ? v : expm1f(v);
    if constexpr (OUTBF)
        ((unsigned short*)outp)[(size_t)node * 64 + lane] = (unsigned short)f2bf(v);
    else
        ((float*)outp)[(size_t)node * 64 + lane] = v;
}

// ----------------------------- head (fp32 VALU) ------------------------------
template<int F, int NOUT>
__global__ void head_kernel(const float* __restrict__ A,
                            const float* __restrict__ W,
                            const float* __restrict__ bias,
                            float* __restrict__ out, int nN) {
    constexpr int NCH = F / 32;
    __shared__ float As[64][36];
    __shared__ float Bs[32][64];

    const int t = threadIdx.x;
    const int block0 = blockIdx.x * 64;
    const int tm = (t >> 4) << 2;
    const int tn = (t & 15) << 2;

    float acc[4][4] = {};

    for (int ch = 0; ch < NCH; ++ch) {
        const int kg0 = ch * 32;
        {
            const int kk = (t & 7) * 4;
#pragma unroll
            for (int r = 0; r < 2; ++r) {
                const int n = (t >> 3) + r * 32;
                const int node = block0 + n;
                float4 v = make_float4(0.f, 0.f, 0.f, 0.f);
                if (node < nN)
                    v = *reinterpret_cast<const float4*>(A + (size_t)node * F + kg0 + kk);
                *reinterpret_cast<float4*>(&As[n][kk]) = v;
            }
        }
        {
            const int j = t & 63;
#pragma unroll
            for (int p = 0; p < 8; ++p) {
                const int kk = (t >> 6) + p * 4;
                Bs[kk][j] = (j < NOUT) ? W[(size_t)j * F + kg0 + kk] : 0.0f;
            }
        }
        __syncthreads();
#pragma unroll
        for (int kk = 0; kk < 32; ++kk) {
            const float a0 = As[tm + 0][kk];
            const float a1 = As[tm + 1][kk];
            const float a2 = As[tm + 2][kk];
            const float a3 = As[tm + 3][kk];
            const float4 bv = *reinterpret_cast<const float4*>(&Bs[kk][tn]);
            acc[0][0] += a0 * bv.x; acc[0][1] += a0 * bv.y; acc[0][2] += a0 * bv.z; acc[0][3] += a0 * bv.w;
            acc[1][0] += a1 * bv.x; acc[1][1] += a1 * bv.y; acc[1][2] += a1 * bv.z; acc[1][3] += a1 * bv.w;
            acc[2][0] += a2 * bv.x; acc[2][1] += a2 * bv.y; acc[2][2] += a2 * bv.z; acc[2][3] += a2 * bv.w;
            acc[3][0] += a3 * bv.x; acc[3][1] += a3 * bv.y; acc[3][2] += a3 * bv.z; acc[3][3] += a3 * bv.w;
        }
        __syncthreads();
    }

#pragma unroll
    for (int i = 0; i < 4; ++i) {
        const int node = block0 + tm + i;
        if (node >= nN) continue;
#pragma unroll
        for (int j = 0; j < 4; ++j) {
            const int col = tn + j;
            if (col < NOUT)
                out[(size_t)node * NOUT + col] = acc[i][j] + bias[col];
        }
    }
}

// ----------------------------- launch ---------------------------------------

extern "C" void kernel_launch(void* const* d_in, const int* in_sizes, int n_in,
                              void* d_out, int out_size, void* d_ws, size_t ws_size,
                              hipStream_t stream) {
    const float* x    = (const float*)d_in[0];
    const int*   ei   = (const int*)d_in[1];
    const float* W1l  = (const float*)d_in[2];
    const float* b1   = (const float*)d_in[3];
    const float* W1r  = (const float*)d_in[4];
    const float* W2l  = (const float*)d_in[5];
    const float* b2   = (const float*)d_in[6];
    const float* W2r  = (const float*)d_in[7];
    const float* W3l  = (const float*)d_in[8];
    const float* b3   = (const float*)d_in[9];
    const float* W3r  = (const float*)d_in[10];
    const float* Wout = (const float*)d_in[11];
    const float* bout = (const float*)d_in[12];

    const int N = in_sizes[0] / 128;   // 100000
    const int E = in_sizes[1] / 2;     // 1600000
    const int* src  = ei;
    const int* dstA = ei + E;

    char* ws = (char*)d_ws;
    size_t o = 0;
    int* degi    = (int*)(ws + o); o += ws_align((size_t)N * 4);
    int* partial = (int*)(ws + o); o += ws_align(4096);
    int* rowptr  = (int*)(ws + o); o += ws_align((size_t)(N + 1) * 4);
    int* cursor  = (int*)(ws + o); o += ws_align((size_t)N * 4);
    int* csr     = (int*)(ws + o); o += ws_align((size_t)E * 4);
    unsigned short* xl  = (unsigned short*)(ws + o); o += ws_align((size_t)N * 64 * 2);
    float*          xr  = (float*)(ws + o);          o += ws_align((size_t)N * 64 * 4);
    unsigned short* hAb = (unsigned short*)(ws + o); o += ws_align((size_t)N * 64 * 2);
    unsigned short* hBb = (unsigned short*)(ws + o); o += ws_align((size_t)N * 64 * 2);
    float*          h3f = (float*)(ws + o);          o += ws_align((size_t)N * 64 * 4);
    float* outp = (float*)d_out;

    const int nb = (N + 1023) / 1024;
    const int projGrid = (N + 127) / 128;
    const int gatherGrid = (N + 3) / 4;
    const int headGrid = (N + 63) / 64;

    // ---- CSR build ----
    zero_kernel<<<(N + 255) / 256, 256, 0, stream>>>(degi, N);
    count_deg_int<<<(E + 255) / 256, 256, 0, stream>>>(dstA, degi, E, N);
    block_sum_kernel<<<nb, 256, 0, stream>>>(degi, partial, N);
    scan_partial_kernel<<<1, 64, 0, stream>>>(partial, nb);
    block_scan_kernel<<<nb, 256, 0, stream>>>(degi, partial, rowptr, cursor, N, E);
    fill_csr_kernel<<<(E + 255) / 256, 256, 0, stream>>>(src, dstA, cursor, csr, E, N);

    // ---- layer 1 (128 -> 64, ELU) ----
    proj2_mfma<128, true><<<projGrid, 256, 0, stream>>>(x, W1l, W1r, b1, xl, xr, N);
    gather_kernel<true, true><<<gatherGrid, 256, 0, stream>>>(xl, xr, rowptr, csr, hAb, N, E);

    // ---- layer 2 (64 -> 64, ELU) ----
    proj2_mfma<64, false><<<projGrid, 256, 0, stream>>>(hAb, W2l, W2r, b2, xl, xr, N);
    gather_kernel<true, true><<<gatherGrid, 256, 0, stream>>>(xl, xr, rowptr, csr, hBb, N, E);

    // ---- layer 3 (64 -> 64, no ELU) ----
    proj2_mfma<64, false><<<projGrid, 256, 0, stream>>>(hBb, W3l, W3r, b3, xl, xr, N);
    gather_kernel<false, false><<<gatherGrid, 256, 0, stream>>>(xl, xr, rowptr, csr, h3f, N, E);

    // ---- head (64 -> 40, fp32) ----
    head_kernel<64, 40><<<headGrid, 256, 0, stream>>>(h3f, Wout, bout, outp, N);
}

// Round 5
// 497.011 us; speedup vs baseline: 11.4409x; 1.0660x over previous
//
#include <hip/hip_runtime.h>

// ---------------------------------------------------------------------------
// SAGEConvNet round 4: bucketed CSR build (kills fill_csr line-thrash) +
// parallel partial scan + bf16 h3. Feature pipeline unchanged from R3:
// MFMA dual projections (bf16 in, fp32 acc), bf16 gather payload.
// ---------------------------------------------------------------------------

static inline size_t ws_align(size_t x) { return (x + 511) & ~size_t(511); }

using frag_ab = __attribute__((ext_vector_type(8))) short;   // 8 bf16
using f32x4   = __attribute__((ext_vector_type(4))) float;   // 4 fp32 acc
using us4     = __attribute__((ext_vector_type(4))) unsigned short;

__device__ inline short f2bf(float f) {            // RNE fp32 -> bf16
    unsigned u = __builtin_bit_cast(unsigned, f);
    u += 0x7fff + ((u >> 16) & 1);
    return (short)(u >> 16);
}
__device__ inline float b2f(unsigned short h) {
    unsigned u = ((unsigned)h) << 16;
    return __builtin_bit_cast(float, u);
}

// ----------------------------- utility --------------------------------------

__global__ void zero_kernel(int* __restrict__ p, int n) {
    int i = blockIdx.x * blockDim.x + threadIdx.x;
    if (i < n) p[i] = 0;
}

// ----------------------------- CSR build -----------------------------------

__global__ void count_deg_int(const int* __restrict__ dst, int* __restrict__ degi,
                              int nE, int nN) {
    int e = blockIdx.x * blockDim.x + threadIdx.x;
    if (e < nE) {
        const unsigned d = (unsigned)dst[e];
        if (d < (unsigned)nN) atomicAdd(&degi[d], 1);
    }
}

__global__ void block_sum_kernel(const int* __restrict__ degi, int* __restrict__ partial, int N) {
    __shared__ int sdata[256];
    const int t = threadIdx.x;
    const int base = blockIdx.x * 1024 + t * 4;
    int s = 0;
#pragma unroll
    for (int q = 0; q < 4; ++q) {
        const int i = base + q;
        if (i < N) s += degi[i];
    }
    sdata[t] = s;
    __syncthreads();
    for (int off = 128; off > 0; off >>= 1) {
        if (t < off) sdata[t] += sdata[t + off];
        __syncthreads();
    }
    if (t == 0) partial[blockIdx.x] = sdata[0];
}

// parallel exclusive scan of up to 1024 partials (one block, 256 threads x 4)
__global__ void scan_partial_par(int* __restrict__ partial, int nb) {
    __shared__ int sdata[256];
    const int t = threadIdx.x;
    const int base = t * 4;
    int v[4];
    int tsum = 0;
#pragma unroll
    for (int q = 0; q < 4; ++q) {
        const int i = base + q;
        v[q] = (i < nb) ? partial[i] : 0;
        tsum += v[q];
    }
    sdata[t] = tsum;
    __syncthreads();
    for (int off = 1; off < 256; off <<= 1) {
        int add = (t >= off) ? sdata[t - off] : 0;
        __syncthreads();
        sdata[t] += add;
        __syncthreads();
    }
    int run = sdata[t] - tsum;   // exclusive prefix for this thread's chunk
#pragma unroll
    for (int q = 0; q < 4; ++q) {
        const int i = base + q;
        if (i < nb) { partial[i] = run; run += v[q]; }
    }
}

__global__ void block_scan_kernel(const int* __restrict__ degi, const int* __restrict__ partial,
                                  int* __restrict__ rowptr, int* __restrict__ cursor,
                                  int N, int E) {
    __shared__ int sdata[256];
    const int t = threadIdx.x;
    const int base = blockIdx.x * 1024 + t * 4;
    int v[4];
    int tsum = 0;
#pragma unroll
    for (int q = 0; q < 4; ++q) {
        const int i = base + q;
        v[q] = (i < N) ? degi[i] : 0;
        tsum += v[q];
    }
    sdata[t] = tsum;
    __syncthreads();
    for (int off = 1; off < 256; off <<= 1) {
        int add = (t >= off) ? sdata[t - off] : 0;
        __syncthreads();
        sdata[t] += add;
        __syncthreads();
    }
    int run = partial[blockIdx.x] + sdata[t] - tsum;
#pragma unroll
    for (int q = 0; q < 4; ++q) {
        const int i = base + q;
        if (i < N) { rowptr[i] = run; cursor[i] = run; run += v[q]; }
    }
    if (blockIdx.x == 0 && t == 0) rowptr[N] = E;
}

// ---- bucketed edge scatter: bucket = 64 consecutive dst nodes. -------------
// Writes land near ~NB moving cursors -> L2 line merging -> ~8B/edge HBM.
__global__ void pass1_scatter(const int* __restrict__ src, const int* __restrict__ dst,
                              const int* __restrict__ rowptr, int* __restrict__ bcur,
                              uint2* __restrict__ ebuf, int nE, int nN) {
    int e = blockIdx.x * blockDim.x + threadIdx.x;
    if (e >= nE) return;
    const unsigned d = (unsigned)dst[e];
    if (d >= (unsigned)nN) return;
    const int b = (int)(d >> 6);
    const int pos = rowptr[b << 6] + atomicAdd(&bcur[b * 16], 1);  // padded cursors
    if ((unsigned)pos < (unsigned)nE) {
        uint2 ed; ed.x = (unsigned)src[e]; ed.y = d;
        ebuf[pos] = ed;
    }
}

// ---- per-bucket CSR finalize: LDS scatter, sequential global write. --------
#define P2CAP 2048
__global__ void pass2_build(const uint2* __restrict__ ebuf, const int* __restrict__ rowptr,
                            int* __restrict__ gcur, int* __restrict__ csr,
                            int nN, int nE) {
    __shared__ int lcur[64];
    __shared__ int lcsr[P2CAP];
    const int b = blockIdx.x;
    const int node0 = b << 6;
    const int nloc = min(64, nN - node0);
    if (nloc <= 0) return;
    const int base = rowptr[node0];
    const int end  = rowptr[node0 + nloc];
    const int cnt  = end - base;
    const int t = threadIdx.x;
    if (t < 64) lcur[t] = (t < nloc) ? (rowptr[node0 + t] - base) : 0;
    __syncthreads();
    if (cnt <= P2CAP) {
        for (int i = t; i < cnt; i += blockDim.x) {
            const uint2 ed = ebuf[base + i];
            const int l = (int)ed.y - node0;
            if ((unsigned)l < 64u) {
                const int pos = atomicAdd(&lcur[l], 1);
                if ((unsigned)pos < (unsigned)P2CAP) lcsr[pos] = (int)ed.x;
            }
        }
        __syncthreads();
        for (int i = t; i < cnt; i += blockDim.x) csr[base + i] = lcsr[i];
    } else {
        // containment fallback (not expected on this graph)
        for (int i = t; i < cnt; i += blockDim.x) {
            const uint2 ed = ebuf[base + i];
            if (ed.y < (unsigned)nN) {
                const int pos = atomicAdd(&gcur[ed.y], 1);
                if ((unsigned)pos < (unsigned)nE) csr[pos] = (int)ed.x;
            }
        }
    }
}

// --------------------- dual projection via bf16 MFMA -------------------------
template<int F, bool AF32>
__global__ void proj2_mfma(const void* __restrict__ Aptr,
                           const float* __restrict__ Wl,
                           const float* __restrict__ Wr,
                           const float* __restrict__ bias,
                           unsigned short* __restrict__ xl,  // bf16 [N][64]
                           float* __restrict__ xr,           // fp32 [N][64]
                           int nN) {
    const int t    = threadIdx.x;
    const int wave = t >> 6;
    const int lane = t & 63;
    const int lg   = lane >> 4;   // k-group (0..3)
    const int lr   = lane & 15;   // row (A) / col (B,C)
    const int mbase = blockIdx.x * 128 + wave * 32;

    const float*          Af = (const float*)Aptr;
    const unsigned short* Ab = (const unsigned short*)Aptr;

    f32x4 accl[2][4] = {};
    f32x4 accr[2][4] = {};

#pragma unroll
    for (int ks = 0; ks < F / 32; ++ks) {
        const int k0 = ks * 32 + lg * 8;
        frag_ab afr[2];
#pragma unroll
        for (int mf = 0; mf < 2; ++mf) {
            int row = mbase + mf * 16 + lr;
            if (row >= nN) row = nN - 1;           // clamp; tail rows masked at store
            if constexpr (AF32) {
                const float4 f0 = *reinterpret_cast<const float4*>(Af + (size_t)row * F + k0);
                const float4 f1 = *reinterpret_cast<const float4*>(Af + (size_t)row * F + k0 + 4);
                frag_ab a;
                a[0] = f2bf(f0.x); a[1] = f2bf(f0.y); a[2] = f2bf(f0.z); a[3] = f2bf(f0.w);
                a[4] = f2bf(f1.x); a[5] = f2bf(f1.y); a[6] = f2bf(f1.z); a[7] = f2bf(f1.w);
                afr[mf] = a;
            } else {
                afr[mf] = *reinterpret_cast<const frag_ab*>(Ab + (size_t)row * F + k0);
            }
        }
#pragma unroll
        for (int nf = 0; nf < 4; ++nf) {
            const int col = nf * 16 + lr;
            const float4 l0 = *reinterpret_cast<const float4*>(Wl + (size_t)col * F + k0);
            const float4 l1 = *reinterpret_cast<const float4*>(Wl + (size_t)col * F + k0 + 4);
            const float4 r0 = *reinterpret_cast<const float4*>(Wr + (size_t)col * F + k0);
            const float4 r1 = *reinterpret_cast<const float4*>(Wr + (size_t)col * F + k0 + 4);
            frag_ab bl, br;
            bl[0] = f2bf(l0.x); bl[1] = f2bf(l0.y); bl[2] = f2bf(l0.z); bl[3] = f2bf(l0.w);
            bl[4] = f2bf(l1.x); bl[5] = f2bf(l1.y); bl[6] = f2bf(l1.z); bl[7] = f2bf(l1.w);
            br[0] = f2bf(r0.x); br[1] = f2bf(r0.y); br[2] = f2bf(r0.z); br[3] = f2bf(r0.w);
            br[4] = f2bf(r1.x); br[5] = f2bf(r1.y); br[6] = f2bf(r1.z); br[7] = f2bf(r1.w);
            accl[0][nf] = __builtin_amdgcn_mfma_f32_16x16x32_bf16(afr[0], bl, accl[0][nf], 0, 0, 0);
            accl[1][nf] = __builtin_amdgcn_mfma_f32_16x16x32_bf16(afr[1], bl, accl[1][nf], 0, 0, 0);
            accr[0][nf] = __builtin_amdgcn_mfma_f32_16x16x32_bf16(afr[0], br, accr[0][nf], 0, 0, 0);
            accr[1][nf] = __builtin_amdgcn_mfma_f32_16x16x32_bf16(afr[1], br, accr[1][nf], 0, 0, 0);
        }
    }

    // C/D layout: col=lane&15, row=(lane>>4)*4+reg   [m89-verified]
#pragma unroll
    for (int mf = 0; mf < 2; ++mf) {
#pragma unroll
        for (int nf = 0; nf < 4; ++nf) {
            const int col = nf * 16 + lr;
            const float bv = bias[col];
#pragma unroll
            for (int j = 0; j < 4; ++j) {
                const int row = mbase + mf * 16 + lg * 4 + j;
                if (row < nN) {
                    xl[(size_t)row * 64 + col] = (unsigned short)f2bf(accl[mf][nf][j]);
                    xr[(size_t)row * 64 + col] = accr[mf][nf][j] + bv;
                }
            }
        }
    }
}

// ----------------------------- gather-mean ----------------------------------
template<bool DOELU>
__global__ void gather_kernel(const unsigned short* __restrict__ xl,
                              const float* __restrict__ xr,
                              const int* __restrict__ rowptr, const int* __restrict__ csr,
                              unsigned short* __restrict__ outp, int nN, int nE) {
    const int node = blockIdx.x * (blockDim.x >> 6) + (threadIdx.x >> 6);
    if (node >= nN) return;
    const int lane = threadIdx.x & 63;
    int b = rowptr[node];
    int e = rowptr[node + 1];
    b = max(0, min(b, nE));
    e = max(b, min(e, nE));
    const float d = (float)(e - b);
    float acc = 0.f;
    int i = b;
    for (; i + 4 <= e; i += 4) {
        const unsigned s0 = (unsigned)csr[i + 0];
        const unsigned s1 = (unsigned)csr[i + 1];
        const unsigned s2 = (unsigned)csr[i + 2];
        const unsigned s3 = (unsigned)csr[i + 3];
        acc += b2f(xl[(size_t)s0 * 64 + lane]) + b2f(xl[(size_t)s1 * 64 + lane])
             + b2f(xl[(size_t)s2 * 64 + lane]) + b2f(xl[(size_t)s3 * 64 + lane]);
    }
    for (; i < e; ++i) acc += b2f(xl[(size_t)(unsigned)csr[i] * 64 + lane]);
    float v = acc / fmaxf(d, 1.0f) + xr[(size_t)node * 64 + lane];
    if (DOELU) v = v > 0.f ? v : expm1f(v);
    outp[(size_t)node * 64 + lane] = (unsigned short)f2bf(v);
}

// ----------------------------- head (fp32 VALU, bf16 A) ----------------------
template<int F, int NOUT>
__global__ void head_kernel(const unsigned short* __restrict__ A,
                            const float* __restrict__ W,
                            const float* __restrict__ bias,
                            float* __restrict__ out, int nN) {
    constexpr int NCH = F / 32;
    __shared__ float As[64][36];
    __shared__ float Bs[32][64];

    const int t = threadIdx.x;
    const int block0 = blockIdx.x * 64;
    const int tm = (t >> 4) << 2;
    const int tn = (t & 15) << 2;

    float acc[4][4] = {};

    for (int ch = 0; ch < NCH; ++ch) {
        const int kg0 = ch * 32;
        {
            const int kk = (t & 7) * 4;
#pragma unroll
            for (int r = 0; r < 2; ++r) {
                const int n = (t >> 3) + r * 32;
                const int node = block0 + n;
                float4 v = make_float4(0.f, 0.f, 0.f, 0.f);
                if (node < nN) {
                    const us4 u = *reinterpret_cast<const us4*>(A + (size_t)node * F + kg0 + kk);
                    v.x = b2f(u[0]); v.y = b2f(u[1]); v.z = b2f(u[2]); v.w = b2f(u[3]);
                }
                *reinterpret_cast<float4*>(&As[n][kk]) = v;
            }
        }
        {
            const int j = t & 63;
#pragma unroll
            for (int p = 0; p < 8; ++p) {
                const int kk = (t >> 6) + p * 4;
                Bs[kk][j] = (j < NOUT) ? W[(size_t)j * F + kg0 + kk] : 0.0f;
            }
        }
        __syncthreads();
#pragma unroll
        for (int kk = 0; kk < 32; ++kk) {
            const float a0 = As[tm + 0][kk];
            const float a1 = As[tm + 1][kk];
            const float a2 = As[tm + 2][kk];
            const float a3 = As[tm + 3][kk];
            const float4 bv = *reinterpret_cast<const float4*>(&Bs[kk][tn]);
            acc[0][0] += a0 * bv.x; acc[0][1] += a0 * bv.y; acc[0][2] += a0 * bv.z; acc[0][3] += a0 * bv.w;
            acc[1][0] += a1 * bv.x; acc[1][1] += a1 * bv.y; acc[1][2] += a1 * bv.z; acc[1][3] += a1 * bv.w;
            acc[2][0] += a2 * bv.x; acc[2][1] += a2 * bv.y; acc[2][2] += a2 * bv.z; acc[2][3] += a2 * bv.w;
            acc[3][0] += a3 * bv.x; acc[3][1] += a3 * bv.y; acc[3][2] += a3 * bv.z; acc[3][3] += a3 * bv.w;
        }
        __syncthreads();
    }

#pragma unroll
    for (int i = 0; i < 4; ++i) {
        const int node = block0 + tm + i;
        if (node >= nN) continue;
#pragma unroll
        for (int j = 0; j < 4; ++j) {
            const int col = tn + j;
            if (col < NOUT)
                out[(size_t)node * NOUT + col] = acc[i][j] + bias[col];
        }
    }
}

// ----------------------------- launch ---------------------------------------

extern "C" void kernel_launch(void* const* d_in, const int* in_sizes, int n_in,
                              void* d_out, int out_size, void* d_ws, size_t ws_size,
                              hipStream_t stream) {
    const float* x    = (const float*)d_in[0];
    const int*   ei   = (const int*)d_in[1];
    const float* W1l  = (const float*)d_in[2];
    const float* b1   = (const float*)d_in[3];
    const float* W1r  = (const float*)d_in[4];
    const float* W2l  = (const float*)d_in[5];
    const float* b2   = (const float*)d_in[6];
    const float* W2r  = (const float*)d_in[7];
    const float* W3l  = (const float*)d_in[8];
    const float* b3   = (const float*)d_in[9];
    const float* W3r  = (const float*)d_in[10];
    const float* Wout = (const float*)d_in[11];
    const float* bout = (const float*)d_in[12];

    const int N = in_sizes[0] / 128;   // 100000
    const int E = in_sizes[1] / 2;     // 1600000
    const int* src  = ei;
    const int* dstA = ei + E;
    const int NB = (N + 63) / 64;      // buckets (64 nodes each)

    char* ws = (char*)d_ws;
    size_t o = 0;
    int* degi    = (int*)(ws + o); o += ws_align((size_t)N * 4);
    int* bcur    = (int*)(ws + o); o += ws_align((size_t)NB * 16 * 4);   // padded cursors
    int* partial = (int*)(ws + o); o += ws_align(4096);
    int* rowptr  = (int*)(ws + o); o += ws_align((size_t)(N + 1) * 4);
    int* cursor  = (int*)(ws + o); o += ws_align((size_t)N * 4);
    int* csr     = (int*)(ws + o); o += ws_align((size_t)E * 4);
    uint2* ebuf  = (uint2*)(ws + o); o += ws_align((size_t)E * 8);
    unsigned short* xl  = (unsigned short*)(ws + o); o += ws_align((size_t)N * 64 * 2);
    float*          xr  = (float*)(ws + o);          o += ws_align((size_t)N * 64 * 4);
    unsigned short* hAb = (unsigned short*)(ws + o); o += ws_align((size_t)N * 64 * 2);
    unsigned short* hBb = (unsigned short*)(ws + o); o += ws_align((size_t)N * 64 * 2);
    unsigned short* h3b = (unsigned short*)(ws + o); o += ws_align((size_t)N * 64 * 2);
    float* outp = (float*)d_out;

    const int nb = (N + 1023) / 1024;
    const int projGrid = (N + 127) / 128;
    const int gatherGrid = (N + 3) / 4;
    const int headGrid = (N + 63) / 64;

    // ---- CSR build (bucketed) ----
    // degi and bcur are contiguous: zero both in one launch
    const int ztot = (int)(ws_align((size_t)N * 4) / 4) + NB * 16;
    zero_kernel<<<(ztot + 255) / 256, 256, 0, stream>>>(degi, ztot);
    count_deg_int<<<(E + 255) / 256, 256, 0, stream>>>(dstA, degi, E, N);
    block_sum_kernel<<<nb, 256, 0, stream>>>(degi, partial, N);
    scan_partial_par<<<1, 256, 0, stream>>>(partial, nb);
    block_scan_kernel<<<nb, 256, 0, stream>>>(degi, partial, rowptr, cursor, N, E);
    pass1_scatter<<<(E + 255) / 256, 256, 0, stream>>>(src, dstA, rowptr, bcur, ebuf, E, N);
    pass2_build<<<NB, 256, 0, stream>>>(ebuf, rowptr, cursor, csr, N, E);

    // ---- layer 1 (128 -> 64, ELU) ----
    proj2_mfma<128, true><<<projGrid, 256, 0, stream>>>(x, W1l, W1r, b1, xl, xr, N);
    gather_kernel<true><<<gatherGrid, 256, 0, stream>>>(xl, xr, rowptr, csr, hAb, N, E);

    // ---- layer 2 (64 -> 64, ELU) ----
    proj2_mfma<64, false><<<projGrid, 256, 0, stream>>>(hAb, W2l, W2r, b2, xl, xr, N);
    gather_kernel<true><<<gatherGrid, 256, 0, stream>>>(xl, xr, rowptr, csr, hBb, N, E);

    // ---- layer 3 (64 -> 64, no ELU) ----
    proj2_mfma<64, false><<<projGrid, 256, 0, stream>>>(hBb, W3l, W3r, b3, xl, xr, N);
    gather_kernel<false><<<gatherGrid, 256, 0, stream>>>(xl, xr, rowptr, csr, h3b, N, E);

    // ---- head (64 -> 40, fp32 math, bf16 input) ----
    head_kernel<64, 40><<<headGrid, 256, 0, stream>>>(h3b, Wout, bout, outp, N);
}

// Round 6
// 384.325 us; speedup vs baseline: 14.7954x; 1.2932x over previous
//
#include <hip/hip_runtime.h>

// ---------------------------------------------------------------------------
// SAGEConvNet round 5: LDS-staged binned CSR build.
//   pass1_bin:  block bins 4096 edges into per-bucket LDS buffers (bucket =
//               1024 dst nodes), bulk-flushes coalesced bursts to reserved
//               cursor slots in fixed-capacity bucket regions (ebuf).
//   scan_buckets: 1-block LDS scan of bucket counts -> bbase.
//   pass2_build: block per bucket: LDS histogram -> rowptr (replaces the whole
//               count/scan chain), then scatter csr inside the block-owned
//               64KB window (L2-merged writes, single-XCD owner).
// Feature pipeline unchanged: MFMA dual projections, bf16 gather payload.
// ---------------------------------------------------------------------------

static inline size_t ws_align(size_t x) { return (x + 511) & ~size_t(511); }

#define MAXBC  104     // max coarse buckets supported (N <= 104*1024)
#define CAPL   96      // LDS slots per bucket per block (avg fill ~42)
#define EB_CAP 24576   // ebuf region capacity per bucket (mean 16384, +64 sigma)

using frag_ab = __attribute__((ext_vector_type(8))) short;   // 8 bf16
using f32x4   = __attribute__((ext_vector_type(4))) float;   // 4 fp32 acc
using us4     = __attribute__((ext_vector_type(4))) unsigned short;

__device__ inline short f2bf(float f) {            // RNE fp32 -> bf16
    unsigned u = __builtin_bit_cast(unsigned, f);
    u += 0x7fff + ((u >> 16) & 1);
    return (short)(u >> 16);
}
__device__ inline float b2f(unsigned short h) {
    unsigned u = ((unsigned)h) << 16;
    return __builtin_bit_cast(float, u);
}

// ----------------------------- utility --------------------------------------

__global__ void zero_kernel(int* __restrict__ p, int n) {
    int i = blockIdx.x * blockDim.x + threadIdx.x;
    if (i < n) p[i] = 0;
}

// ----------------------------- CSR build ------------------------------------

// Bin 4096 edges/block into LDS bucket buffers; bulk-flush per bucket.
__global__ void pass1_bin(const int* __restrict__ src, const int* __restrict__ dst,
                          int* __restrict__ bcur, unsigned* __restrict__ ebuf,
                          int nE, int nN, int nbc) {
    __shared__ unsigned lbuf[MAXBC][CAPL];
    __shared__ int bcnt[MAXBC];
    __shared__ int gbase[MAXBC];
    const int t = threadIdx.x;
    const int e0 = blockIdx.x * 4096;
    for (int i = t; i < MAXBC; i += 256) bcnt[i] = 0;
    __syncthreads();
#pragma unroll
    for (int q = 0; q < 16; ++q) {
        const int e = e0 + q * 256 + t;
        if (e < nE) {
            const unsigned d = (unsigned)dst[e];
            const unsigned s = (unsigned)src[e];
            if (d < (unsigned)nN && s < (unsigned)nN) {
                const int cb = (int)(d >> 10);
                const unsigned v = ((d & 1023u) << 17) | s;
                const int pos = atomicAdd(&bcnt[cb], 1);
                if (pos < CAPL) {
                    lbuf[cb][pos] = v;
                } else {
                    // rare overflow: direct global append (contained)
                    const int gp = atomicAdd(&bcur[cb], 1);
                    if (gp < EB_CAP) ebuf[(size_t)cb * EB_CAP + gp] = v;
                }
            }
        }
    }
    __syncthreads();
    // reserve contiguous global slots per bucket
    for (int b = t; b < nbc; b += 256) {
        const int cnt = min(bcnt[b], CAPL);
        bcnt[b] = cnt;
        gbase[b] = (cnt > 0) ? atomicAdd(&bcur[b], cnt) : 0;
    }
    __syncthreads();
    // cooperative coalesced flush: wave w handles buckets w, w+4, ...
    const int wid = t >> 6, lane = t & 63;
    for (int b = wid; b < nbc; b += 4) {
        const int cnt = bcnt[b];
        const int gb = gbase[b];
        for (int i = lane; i < cnt; i += 64) {
            const int gp = gb + i;
            if (gp < EB_CAP) ebuf[(size_t)b * EB_CAP + gp] = lbuf[b][i];
        }
    }
}

// exclusive scan of bucket counts (single block, nbc <= 256)
__global__ void scan_buckets(const int* __restrict__ bcur, int* __restrict__ bbase, int nbc) {
    __shared__ int sdata[256];
    const int t = threadIdx.x;
    const int v = (t < nbc) ? min(bcur[t], EB_CAP) : 0;
    sdata[t] = v;
    __syncthreads();
    for (int off = 1; off < 256; off <<= 1) {
        int add = (t >= off) ? sdata[t - off] : 0;
        __syncthreads();
        sdata[t] += add;
        __syncthreads();
    }
    if (t < nbc) bbase[t] = sdata[t] - v;   // exclusive
}

// per-bucket: histogram -> rowptr, then csr scatter into block-owned window.
__global__ void pass2_build(const unsigned* __restrict__ ebuf,
                            const int* __restrict__ bcur, const int* __restrict__ bbase,
                            int* __restrict__ rowptr, int* __restrict__ csr,
                            int nN, int nbc) {
    __shared__ int lcnt[1024];
    __shared__ int lcur[1024];
    __shared__ int sdata[256];
    const int b = blockIdx.x;
    const int node0 = b << 10;
    const int nloc = min(1024, nN - node0);
    if (nloc <= 0) return;
    const int cnt  = min(bcur[b], EB_CAP);
    const int base = bbase[b];
    const int t = threadIdx.x;
    const unsigned* eb = ebuf + (size_t)b * EB_CAP;

    for (int i = t; i < 1024; i += 256) lcnt[i] = 0;
    __syncthreads();
    for (int i = t; i < cnt; i += 256) atomicAdd(&lcnt[eb[i] >> 17], 1);
    __syncthreads();
    // exclusive scan of 1024 counts (256 threads x 4)
    int v[4];
    int tsum = 0;
#pragma unroll
    for (int q = 0; q < 4; ++q) { v[q] = lcnt[t * 4 + q]; tsum += v[q]; }
    sdata[t] = tsum;
    __syncthreads();
    for (int off = 1; off < 256; off <<= 1) {
        int add = (t >= off) ? sdata[t - off] : 0;
        __syncthreads();
        sdata[t] += add;
        __syncthreads();
    }
    int run = sdata[t] - tsum;
#pragma unroll
    for (int q = 0; q < 4; ++q) {
        const int l = t * 4 + q;
        lcur[l] = run;
        if (l < nloc) rowptr[node0 + l] = base + run;
        run += v[q];
    }
    if (b == nbc - 1 && t == 0) rowptr[nN] = base + cnt;
    __syncthreads();
    // scatter into the block-owned csr window (<=96KB contiguous; L2-merged)
    for (int i = t; i < cnt; i += 256) {
        const unsigned ev = eb[i];
        const int pos = atomicAdd(&lcur[ev >> 17], 1);
        csr[base + pos] = (int)(ev & 0x1FFFFu);
    }
}

// --------------------- dual projection via bf16 MFMA -------------------------
template<int F, bool AF32>
__global__ void proj2_mfma(const void* __restrict__ Aptr,
                           const float* __restrict__ Wl,
                           const float* __restrict__ Wr,
                           const float* __restrict__ bias,
                           unsigned short* __restrict__ xl,  // bf16 [N][64]
                           float* __restrict__ xr,           // fp32 [N][64]
                           int nN) {
    const int t    = threadIdx.x;
    const int wave = t >> 6;
    const int lane = t & 63;
    const int lg   = lane >> 4;   // k-group (0..3)
    const int lr   = lane & 15;   // row (A) / col (B,C)
    const int mbase = blockIdx.x * 128 + wave * 32;

    const float*          Af = (const float*)Aptr;
    const unsigned short* Ab = (const unsigned short*)Aptr;

    f32x4 accl[2][4] = {};
    f32x4 accr[2][4] = {};

#pragma unroll
    for (int ks = 0; ks < F / 32; ++ks) {
        const int k0 = ks * 32 + lg * 8;
        frag_ab afr[2];
#pragma unroll
        for (int mf = 0; mf < 2; ++mf) {
            int row = mbase + mf * 16 + lr;
            if (row >= nN) row = nN - 1;           // clamp; tail rows masked at store
            if constexpr (AF32) {
                const float4 f0 = *reinterpret_cast<const float4*>(Af + (size_t)row * F + k0);
                const float4 f1 = *reinterpret_cast<const float4*>(Af + (size_t)row * F + k0 + 4);
                frag_ab a;
                a[0] = f2bf(f0.x); a[1] = f2bf(f0.y); a[2] = f2bf(f0.z); a[3] = f2bf(f0.w);
                a[4] = f2bf(f1.x); a[5] = f2bf(f1.y); a[6] = f2bf(f1.z); a[7] = f2bf(f1.w);
                afr[mf] = a;
            } else {
                afr[mf] = *reinterpret_cast<const frag_ab*>(Ab + (size_t)row * F + k0);
            }
        }
#pragma unroll
        for (int nf = 0; nf < 4; ++nf) {
            const int col = nf * 16 + lr;
            const float4 l0 = *reinterpret_cast<const float4*>(Wl + (size_t)col * F + k0);
            const float4 l1 = *reinterpret_cast<const float4*>(Wl + (size_t)col * F + k0 + 4);
            const float4 r0 = *reinterpret_cast<const float4*>(Wr + (size_t)col * F + k0);
            const float4 r1 = *reinterpret_cast<const float4*>(Wr + (size_t)col * F + k0 + 4);
            frag_ab bl, br;
            bl[0] = f2bf(l0.x); bl[1] = f2bf(l0.y); bl[2] = f2bf(l0.z); bl[3] = f2bf(l0.w);
            bl[4] = f2bf(l1.x); bl[5] = f2bf(l1.y); bl[6] = f2bf(l1.z); bl[7] = f2bf(l1.w);
            br[0] = f2bf(r0.x); br[1] = f2bf(r0.y); br[2] = f2bf(r0.z); br[3] = f2bf(r0.w);
            br[4] = f2bf(r1.x); br[5] = f2bf(r1.y); br[6] = f2bf(r1.z); br[7] = f2bf(r1.w);
            accl[0][nf] = __builtin_amdgcn_mfma_f32_16x16x32_bf16(afr[0], bl, accl[0][nf], 0, 0, 0);
            accl[1][nf] = __builtin_amdgcn_mfma_f32_16x16x32_bf16(afr[1], bl, accl[1][nf], 0, 0, 0);
            accr[0][nf] = __builtin_amdgcn_mfma_f32_16x16x32_bf16(afr[0], br, accr[0][nf], 0, 0, 0);
            accr[1][nf] = __builtin_amdgcn_mfma_f32_16x16x32_bf16(afr[1], br, accr[1][nf], 0, 0, 0);
        }
    }

    // C/D layout: col=lane&15, row=(lane>>4)*4+reg   [m89-verified]
#pragma unroll
    for (int mf = 0; mf < 2; ++mf) {
#pragma unroll
        for (int nf = 0; nf < 4; ++nf) {
            const int col = nf * 16 + lr;
            const float bv = bias[col];
#pragma unroll
            for (int j = 0; j < 4; ++j) {
                const int row = mbase + mf * 16 + lg * 4 + j;
                if (row < nN) {
                    xl[(size_t)row * 64 + col] = (unsigned short)f2bf(accl[mf][nf][j]);
                    xr[(size_t)row * 64 + col] = accr[mf][nf][j] + bv;
                }
            }
        }
    }
}

// ----------------------------- gather-mean ----------------------------------
template<bool DOELU>
__global__ void gather_kernel(const unsigned short* __restrict__ xl,
                              const float* __restrict__ xr,
                              const int* __restrict__ rowptr, const int* __restrict__ csr,
                              unsigned short* __restrict__ outp, int nN, int nE) {
    const int node = blockIdx.x * (blockDim.x >> 6) + (threadIdx.x >> 6);
    if (node >= nN) return;
    const int lane = threadIdx.x & 63;
    int b = rowptr[node];
    int e = rowptr[node + 1];
    b = max(0, min(b, nE));
    e = max(b, min(e, nE));
    const float d = (float)(e - b);
    float acc = 0.f;
    int i = b;
    for (; i + 4 <= e; i += 4) {
        const unsigned s0 = (unsigned)csr[i + 0];
        const unsigned s1 = (unsigned)csr[i + 1];
        const unsigned s2 = (unsigned)csr[i + 2];
        const unsigned s3 = (unsigned)csr[i + 3];
        acc += b2f(xl[(size_t)s0 * 64 + lane]) + b2f(xl[(size_t)s1 * 64 + lane])
             + b2f(xl[(size_t)s2 * 64 + lane]) + b2f(xl[(size_t)s3 * 64 + lane]);
    }
    for (; i < e; ++i) acc += b2f(xl[(size_t)(unsigned)csr[i] * 64 + lane]);
    float v = acc / fmaxf(d, 1.0f) + xr[(size_t)node * 64 + lane];
    if (DOELU) v = v > 0.f ? v : expm1f(v);
    outp[(size_t)node * 64 + lane] = (unsigned short)f2bf(v);
}

// ----------------------------- head (fp32 VALU, bf16 A) ----------------------
template<int F, int NOUT>
__global__ void head_kernel(const unsigned short* __restrict__ A,
                            const float* __restrict__ W,
                            const float* __restrict__ bias,
                            float* __restrict__ out, int nN) {
    constexpr int NCH = F / 32;
    __shared__ float As[64][36];
    __shared__ float Bs[32][64];

    const int t = threadIdx.x;
    const int block0 = blockIdx.x * 64;
    const int tm = (t >> 4) << 2;
    const int tn = (t & 15) << 2;

    float acc[4][4] = {};

    for (int ch = 0; ch < NCH; ++ch) {
        const int kg0 = ch * 32;
        {
            const int kk = (t & 7) * 4;
#pragma unroll
            for (int r = 0; r < 2; ++r) {
                const int n = (t >> 3) + r * 32;
                const int node = block0 + n;
                float4 v = make_float4(0.f, 0.f, 0.f, 0.f);
                if (node < nN) {
                    const us4 u = *reinterpret_cast<const us4*>(A + (size_t)node * F + kg0 + kk);
                    v.x = b2f(u[0]); v.y = b2f(u[1]); v.z = b2f(u[2]); v.w = b2f(u[3]);
                }
                *reinterpret_cast<float4*>(&As[n][kk]) = v;
            }
        }
        {
            const int j = t & 63;
#pragma unroll
            for (int p = 0; p < 8; ++p) {
                const int kk = (t >> 6) + p * 4;
                Bs[kk][j] = (j < NOUT) ? W[(size_t)j * F + kg0 + kk] : 0.0f;
            }
        }
        __syncthreads();
#pragma unroll
        for (int kk = 0; kk < 32; ++kk) {
            const float a0 = As[tm + 0][kk];
            const float a1 = As[tm + 1][kk];
            const float a2 = As[tm + 2][kk];
            const float a3 = As[tm + 3][kk];
            const float4 bv = *reinterpret_cast<const float4*>(&Bs[kk][tn]);
            acc[0][0] += a0 * bv.x; acc[0][1] += a0 * bv.y; acc[0][2] += a0 * bv.z; acc[0][3] += a0 * bv.w;
            acc[1][0] += a1 * bv.x; acc[1][1] += a1 * bv.y; acc[1][2] += a1 * bv.z; acc[1][3] += a1 * bv.w;
            acc[2][0] += a2 * bv.x; acc[2][1] += a2 * bv.y; acc[2][2] += a2 * bv.z; acc[2][3] += a2 * bv.w;
            acc[3][0] += a3 * bv.x; acc[3][1] += a3 * bv.y; acc[3][2] += a3 * bv.z; acc[3][3] += a3 * bv.w;
        }
        __syncthreads();
    }

#pragma unroll
    for (int i = 0; i < 4; ++i) {
        const int node = block0 + tm + i;
        if (node >= nN) continue;
#pragma unroll
        for (int j = 0; j < 4; ++j) {
            const int col = tn + j;
            if (col < NOUT)
                out[(size_t)node * NOUT + col] = acc[i][j] + bias[col];
        }
    }
}

// ----------------------------- launch ---------------------------------------

extern "C" void kernel_launch(void* const* d_in, const int* in_sizes, int n_in,
                              void* d_out, int out_size, void* d_ws, size_t ws_size,
                              hipStream_t stream) {
    const float* x    = (const float*)d_in[0];
    const int*   ei   = (const int*)d_in[1];
    const float* W1l  = (const float*)d_in[2];
    const float* b1   = (const float*)d_in[3];
    const float* W1r  = (const float*)d_in[4];
    const float* W2l  = (const float*)d_in[5];
    const float* b2   = (const float*)d_in[6];
    const float* W2r  = (const float*)d_in[7];
    const float* W3l  = (const float*)d_in[8];
    const float* b3   = (const float*)d_in[9];
    const float* W3r  = (const float*)d_in[10];
    const float* Wout = (const float*)d_in[11];
    const float* bout = (const float*)d_in[12];

    const int N = in_sizes[0] / 128;   // 100000
    const int E = in_sizes[1] / 2;     // 1600000
    const int* src  = ei;
    const int* dstA = ei + E;
    const int nbc = (N + 1023) >> 10;  // coarse buckets (<= MAXBC for this problem)

    char* ws = (char*)d_ws;
    size_t o = 0;
    int* bcur    = (int*)(ws + o); o += ws_align((size_t)MAXBC * 4);
    int* bbase   = (int*)(ws + o); o += ws_align((size_t)MAXBC * 4);
    int* rowptr  = (int*)(ws + o); o += ws_align((size_t)(N + 1) * 4);
    int* csr     = (int*)(ws + o); o += ws_align((size_t)E * 4);
    unsigned* ebuf = (unsigned*)(ws + o); o += ws_align((size_t)MAXBC * EB_CAP * 4);
    unsigned short* xl  = (unsigned short*)(ws + o); o += ws_align((size_t)N * 64 * 2);
    float*          xr  = (float*)(ws + o);          o += ws_align((size_t)N * 64 * 4);
    unsigned short* hAb = (unsigned short*)(ws + o); o += ws_align((size_t)N * 64 * 2);
    unsigned short* hBb = (unsigned short*)(ws + o); o += ws_align((size_t)N * 64 * 2);
    unsigned short* h3b = (unsigned short*)(ws + o); o += ws_align((size_t)N * 64 * 2);
    float* outp = (float*)d_out;

    const int projGrid = (N + 127) / 128;
    const int gatherGrid = (N + 3) / 4;
    const int headGrid = (N + 63) / 64;

    // ---- CSR build (LDS-staged binning) ----
    zero_kernel<<<1, 256, 0, stream>>>(bcur, MAXBC);
    pass1_bin<<<(E + 4095) / 4096, 256, 0, stream>>>(src, dstA, bcur, ebuf, E, N, nbc);
    scan_buckets<<<1, 256, 0, stream>>>(bcur, bbase, nbc);
    pass2_build<<<nbc, 256, 0, stream>>>(ebuf, bcur, bbase, rowptr, csr, N, nbc);

    // ---- layer 1 (128 -> 64, ELU) ----
    proj2_mfma<128, true><<<projGrid, 256, 0, stream>>>(x, W1l, W1r, b1, xl, xr, N);
    gather_kernel<true><<<gatherGrid, 256, 0, stream>>>(xl, xr, rowptr, csr, hAb, N, E);

    // ---- layer 2 (64 -> 64, ELU) ----
    proj2_mfma<64, false><<<projGrid, 256, 0, stream>>>(hAb, W2l, W2r, b2, xl, xr, N);
    gather_kernel<true><<<gatherGrid, 256, 0, stream>>>(xl, xr, rowptr, csr, hBb, N, E);

    // ---- layer 3 (64 -> 64, no ELU) ----
    proj2_mfma<64, false><<<projGrid, 256, 0, stream>>>(hBb, W3l, W3r, b3, xl, xr, N);
    gather_kernel<false><<<gatherGrid, 256, 0, stream>>>(xl, xr, rowptr, csr, h3b, N, E);

    // ---- head (64 -> 40, fp32 math, bf16 input) ----
    head_kernel<64, 40><<<headGrid, 256, 0, stream>>>(h3b, Wout, bout, outp, N);
}

// Round 7
// 378.088 us; speedup vs baseline: 15.0395x; 1.0165x over previous
//
#include <hip/hip_runtime.h>

// ---------------------------------------------------------------------------
// SAGEConvNet round 6: gather v2 — 4 edges per load instruction.
//   lane = (sub=edge slot 0..3, fp=feature quad 0..15); uint2 (4 bf16) per
//   lane; shfl_xor(16/32) reduce; lanes 0-15 finish + write packed bf16.
// CSR build (LDS-binned) and MFMA projections unchanged from R5.
// ---------------------------------------------------------------------------

static inline size_t ws_align(size_t x) { return (x + 511) & ~size_t(511); }

#define MAXBC  104     // max coarse buckets supported (N <= 104*1024)
#define CAPL   96      // LDS slots per bucket per block (avg fill ~42)
#define EB_CAP 24576   // ebuf region capacity per bucket (mean 16384, +64 sigma)

using frag_ab = __attribute__((ext_vector_type(8))) short;   // 8 bf16
using f32x4   = __attribute__((ext_vector_type(4))) float;   // 4 fp32 acc
using us4     = __attribute__((ext_vector_type(4))) unsigned short;

__device__ inline short f2bf(float f) {            // RNE fp32 -> bf16
    unsigned u = __builtin_bit_cast(unsigned, f);
    u += 0x7fff + ((u >> 16) & 1);
    return (short)(u >> 16);
}
__device__ inline float b2f(unsigned short h) {
    unsigned u = ((unsigned)h) << 16;
    return __builtin_bit_cast(float, u);
}

// ----------------------------- utility --------------------------------------

__global__ void zero_kernel(int* __restrict__ p, int n) {
    int i = blockIdx.x * blockDim.x + threadIdx.x;
    if (i < n) p[i] = 0;
}

// ----------------------------- CSR build ------------------------------------

// Bin 4096 edges/block into LDS bucket buffers; bulk-flush per bucket.
__global__ void pass1_bin(const int* __restrict__ src, const int* __restrict__ dst,
                          int* __restrict__ bcur, unsigned* __restrict__ ebuf,
                          int nE, int nN, int nbc) {
    __shared__ unsigned lbuf[MAXBC][CAPL];
    __shared__ int bcnt[MAXBC];
    __shared__ int gbase[MAXBC];
    const int t = threadIdx.x;
    const int e0 = blockIdx.x * 4096;
    for (int i = t; i < MAXBC; i += 256) bcnt[i] = 0;
    __syncthreads();
#pragma unroll
    for (int q = 0; q < 16; ++q) {
        const int e = e0 + q * 256 + t;
        if (e < nE) {
            const unsigned d = (unsigned)dst[e];
            const unsigned s = (unsigned)src[e];
            if (d < (unsigned)nN && s < (unsigned)nN) {
                const int cb = (int)(d >> 10);
                const unsigned v = ((d & 1023u) << 17) | s;
                const int pos = atomicAdd(&bcnt[cb], 1);
                if (pos < CAPL) {
                    lbuf[cb][pos] = v;
                } else {
                    // rare overflow: direct global append (contained)
                    const int gp = atomicAdd(&bcur[cb], 1);
                    if (gp < EB_CAP) ebuf[(size_t)cb * EB_CAP + gp] = v;
                }
            }
        }
    }
    __syncthreads();
    // reserve contiguous global slots per bucket
    for (int b = t; b < nbc; b += 256) {
        const int cnt = min(bcnt[b], CAPL);
        bcnt[b] = cnt;
        gbase[b] = (cnt > 0) ? atomicAdd(&bcur[b], cnt) : 0;
    }
    __syncthreads();
    // cooperative coalesced flush: wave w handles buckets w, w+4, ...
    const int wid = t >> 6, lane = t & 63;
    for (int b = wid; b < nbc; b += 4) {
        const int cnt = bcnt[b];
        const int gb = gbase[b];
        for (int i = lane; i < cnt; i += 64) {
            const int gp = gb + i;
            if (gp < EB_CAP) ebuf[(size_t)b * EB_CAP + gp] = lbuf[b][i];
        }
    }
}

// exclusive scan of bucket counts (single block, nbc <= 256)
__global__ void scan_buckets(const int* __restrict__ bcur, int* __restrict__ bbase, int nbc) {
    __shared__ int sdata[256];
    const int t = threadIdx.x;
    const int v = (t < nbc) ? min(bcur[t], EB_CAP) : 0;
    sdata[t] = v;
    __syncthreads();
    for (int off = 1; off < 256; off <<= 1) {
        int add = (t >= off) ? sdata[t - off] : 0;
        __syncthreads();
        sdata[t] += add;
        __syncthreads();
    }
    if (t < nbc) bbase[t] = sdata[t] - v;   // exclusive
}

// per-bucket: histogram -> rowptr, then csr scatter into block-owned window.
__global__ void pass2_build(const unsigned* __restrict__ ebuf,
                            const int* __restrict__ bcur, const int* __restrict__ bbase,
                            int* __restrict__ rowptr, int* __restrict__ csr,
                            int nN, int nbc) {
    __shared__ int lcnt[1024];
    __shared__ int lcur[1024];
    __shared__ int sdata[256];
    const int b = blockIdx.x;
    const int node0 = b << 10;
    const int nloc = min(1024, nN - node0);
    if (nloc <= 0) return;
    const int cnt  = min(bcur[b], EB_CAP);
    const int base = bbase[b];
    const int t = threadIdx.x;
    const unsigned* eb = ebuf + (size_t)b * EB_CAP;

    for (int i = t; i < 1024; i += 256) lcnt[i] = 0;
    __syncthreads();
    for (int i = t; i < cnt; i += 256) atomicAdd(&lcnt[eb[i] >> 17], 1);
    __syncthreads();
    // exclusive scan of 1024 counts (256 threads x 4)
    int v[4];
    int tsum = 0;
#pragma unroll
    for (int q = 0; q < 4; ++q) { v[q] = lcnt[t * 4 + q]; tsum += v[q]; }
    sdata[t] = tsum;
    __syncthreads();
    for (int off = 1; off < 256; off <<= 1) {
        int add = (t >= off) ? sdata[t - off] : 0;
        __syncthreads();
        sdata[t] += add;
        __syncthreads();
    }
    int run = sdata[t] - tsum;
#pragma unroll
    for (int q = 0; q < 4; ++q) {
        const int l = t * 4 + q;
        lcur[l] = run;
        if (l < nloc) rowptr[node0 + l] = base + run;
        run += v[q];
    }
    if (b == nbc - 1 && t == 0) rowptr[nN] = base + cnt;
    __syncthreads();
    // scatter into the block-owned csr window (<=96KB contiguous; L2-merged)
    for (int i = t; i < cnt; i += 256) {
        const unsigned ev = eb[i];
        const int pos = atomicAdd(&lcur[ev >> 17], 1);
        csr[base + pos] = (int)(ev & 0x1FFFFu);
    }
}

// --------------------- dual projection via bf16 MFMA -------------------------
template<int F, bool AF32>
__global__ void proj2_mfma(const void* __restrict__ Aptr,
                           const float* __restrict__ Wl,
                           const float* __restrict__ Wr,
                           const float* __restrict__ bias,
                           unsigned short* __restrict__ xl,  // bf16 [N][64]
                           float* __restrict__ xr,           // fp32 [N][64]
                           int nN) {
    const int t    = threadIdx.x;
    const int wave = t >> 6;
    const int lane = t & 63;
    const int lg   = lane >> 4;   // k-group (0..3)
    const int lr   = lane & 15;   // row (A) / col (B,C)
    const int mbase = blockIdx.x * 128 + wave * 32;

    const float*          Af = (const float*)Aptr;
    const unsigned short* Ab = (const unsigned short*)Aptr;

    f32x4 accl[2][4] = {};
    f32x4 accr[2][4] = {};

#pragma unroll
    for (int ks = 0; ks < F / 32; ++ks) {
        const int k0 = ks * 32 + lg * 8;
        frag_ab afr[2];
#pragma unroll
        for (int mf = 0; mf < 2; ++mf) {
            int row = mbase + mf * 16 + lr;
            if (row >= nN) row = nN - 1;           // clamp; tail rows masked at store
            if constexpr (AF32) {
                const float4 f0 = *reinterpret_cast<const float4*>(Af + (size_t)row * F + k0);
                const float4 f1 = *reinterpret_cast<const float4*>(Af + (size_t)row * F + k0 + 4);
                frag_ab a;
                a[0] = f2bf(f0.x); a[1] = f2bf(f0.y); a[2] = f2bf(f0.z); a[3] = f2bf(f0.w);
                a[4] = f2bf(f1.x); a[5] = f2bf(f1.y); a[6] = f2bf(f1.z); a[7] = f2bf(f1.w);
                afr[mf] = a;
            } else {
                afr[mf] = *reinterpret_cast<const frag_ab*>(Ab + (size_t)row * F + k0);
            }
        }
#pragma unroll
        for (int nf = 0; nf < 4; ++nf) {
            const int col = nf * 16 + lr;
            const float4 l0 = *reinterpret_cast<const float4*>(Wl + (size_t)col * F + k0);
            const float4 l1 = *reinterpret_cast<const float4*>(Wl + (size_t)col * F + k0 + 4);
            const float4 r0 = *reinterpret_cast<const float4*>(Wr + (size_t)col * F + k0);
            const float4 r1 = *reinterpret_cast<const float4*>(Wr + (size_t)col * F + k0 + 4);
            frag_ab bl, br;
            bl[0] = f2bf(l0.x); bl[1] = f2bf(l0.y); bl[2] = f2bf(l0.z); bl[3] = f2bf(l0.w);
            bl[4] = f2bf(l1.x); bl[5] = f2bf(l1.y); bl[6] = f2bf(l1.z); bl[7] = f2bf(l1.w);
            br[0] = f2bf(r0.x); br[1] = f2bf(r0.y); br[2] = f2bf(r0.z); br[3] = f2bf(r0.w);
            br[4] = f2bf(r1.x); br[5] = f2bf(r1.y); br[6] = f2bf(r1.z); br[7] = f2bf(r1.w);
            accl[0][nf] = __builtin_amdgcn_mfma_f32_16x16x32_bf16(afr[0], bl, accl[0][nf], 0, 0, 0);
            accl[1][nf] = __builtin_amdgcn_mfma_f32_16x16x32_bf16(afr[1], bl, accl[1][nf], 0, 0, 0);
            accr[0][nf] = __builtin_amdgcn_mfma_f32_16x16x32_bf16(afr[0], br, accr[0][nf], 0, 0, 0);
            accr[1][nf] = __builtin_amdgcn_mfma_f32_16x16x32_bf16(afr[1], br, accr[1][nf], 0, 0, 0);
        }
    }

    // C/D layout: col=lane&15, row=(lane>>4)*4+reg   [m89-verified]
#pragma unroll
    for (int mf = 0; mf < 2; ++mf) {
#pragma unroll
        for (int nf = 0; nf < 4; ++nf) {
            const int col = nf * 16 + lr;
            const float bv = bias[col];
#pragma unroll
            for (int j = 0; j < 4; ++j) {
                const int row = mbase + mf * 16 + lg * 4 + j;
                if (row < nN) {
                    xl[(size_t)row * 64 + col] = (unsigned short)f2bf(accl[mf][nf][j]);
                    xr[(size_t)row * 64 + col] = accr[mf][nf][j] + bv;
                }
            }
        }
    }
}

// ----------------------------- gather-mean v2 --------------------------------
// one wave per node; sub = lane>>4 (edge slot), fp = lane&15 (feature quad).
// One uint2 load (4 bf16) per lane serves 4 edges x 128B per wave instruction.
template<bool DOELU>
__global__ void gather_kernel(const unsigned short* __restrict__ xl,
                              const float* __restrict__ xr,
                              const int* __restrict__ rowptr, const int* __restrict__ csr,
                              unsigned short* __restrict__ outp, int nN, int nE) {
    const int node = blockIdx.x * (blockDim.x >> 6) + (threadIdx.x >> 6);
    if (node >= nN) return;
    const int lane = threadIdx.x & 63;
    const int sub  = lane >> 4;
    const int fp   = lane & 15;
    int b = rowptr[node];
    int e = rowptr[node + 1];
    b = max(0, min(b, nE));
    e = max(b, min(e, nE));
    const float d = (float)(e - b);

    float a0 = 0.f, a1 = 0.f, a2 = 0.f, a3 = 0.f;
    for (int i = b; i < e; i += 4) {
        const int idx = i + sub;
        const bool valid = idx < e;
        const int idc = min(idx, e - 1);            // e > b here, so e-1 >= b
        const unsigned s = (unsigned)csr[idc];
        uint2 u = *reinterpret_cast<const uint2*>(xl + (size_t)s * 64 + fp * 4);
        if (!valid) { u.x = 0u; u.y = 0u; }
        a0 += __builtin_bit_cast(float, u.x << 16);
        a1 += __builtin_bit_cast(float, u.x & 0xffff0000u);
        a2 += __builtin_bit_cast(float, u.y << 16);
        a3 += __builtin_bit_cast(float, u.y & 0xffff0000u);
    }
    // reduce the 4 edge slots (lanes fp, fp+16, fp+32, fp+48)
    a0 += __shfl_xor(a0, 16); a1 += __shfl_xor(a1, 16);
    a2 += __shfl_xor(a2, 16); a3 += __shfl_xor(a3, 16);
    a0 += __shfl_xor(a0, 32); a1 += __shfl_xor(a1, 32);
    a2 += __shfl_xor(a2, 32); a3 += __shfl_xor(a3, 32);

    if (sub == 0) {
        const float inv = 1.0f / fmaxf(d, 1.0f);
        const float4 r = *reinterpret_cast<const float4*>(xr + (size_t)node * 64 + fp * 4);
        float v0 = a0 * inv + r.x;
        float v1 = a1 * inv + r.y;
        float v2 = a2 * inv + r.z;
        float v3 = a3 * inv + r.w;
        if (DOELU) {
            v0 = v0 > 0.f ? v0 : expm1f(v0);
            v1 = v1 > 0.f ? v1 : expm1f(v1);
            v2 = v2 > 0.f ? v2 : expm1f(v2);
            v3 = v3 > 0.f ? v3 : expm1f(v3);
        }
        uint2 p;
        p.x = ((unsigned)(unsigned short)f2bf(v0)) | (((unsigned)(unsigned short)f2bf(v1)) << 16);
        p.y = ((unsigned)(unsigned short)f2bf(v2)) | (((unsigned)(unsigned short)f2bf(v3)) << 16);
        *reinterpret_cast<uint2*>(outp + (size_t)node * 64 + fp * 4) = p;
    }
}

// ----------------------------- head (fp32 VALU, bf16 A) ----------------------
template<int F, int NOUT>
__global__ void head_kernel(const unsigned short* __restrict__ A,
                            const float* __restrict__ W,
                            const float* __restrict__ bias,
                            float* __restrict__ out, int nN) {
    constexpr int NCH = F / 32;
    __shared__ float As[64][36];
    __shared__ float Bs[32][64];

    const int t = threadIdx.x;
    const int block0 = blockIdx.x * 64;
    const int tm = (t >> 4) << 2;
    const int tn = (t & 15) << 2;

    float acc[4][4] = {};

    for (int ch = 0; ch < NCH; ++ch) {
        const int kg0 = ch * 32;
        {
            const int kk = (t & 7) * 4;
#pragma unroll
            for (int r = 0; r < 2; ++r) {
                const int n = (t >> 3) + r * 32;
                const int node = block0 + n;
                float4 v = make_float4(0.f, 0.f, 0.f, 0.f);
                if (node < nN) {
                    const us4 u = *reinterpret_cast<const us4*>(A + (size_t)node * F + kg0 + kk);
                    v.x = b2f(u[0]); v.y = b2f(u[1]); v.z = b2f(u[2]); v.w = b2f(u[3]);
                }
                *reinterpret_cast<float4*>(&As[n][kk]) = v;
            }
        }
        {
            const int j = t & 63;
#pragma unroll
            for (int p = 0; p < 8; ++p) {
                const int kk = (t >> 6) + p * 4;
                Bs[kk][j] = (j < NOUT) ? W[(size_t)j * F + kg0 + kk] : 0.0f;
            }
        }
        __syncthreads();
#pragma unroll
        for (int kk = 0; kk < 32; ++kk) {
            const float a0 = As[tm + 0][kk];
            const float a1 = As[tm + 1][kk];
            const float a2 = As[tm + 2][kk];
            const float a3 = As[tm + 3][kk];
            const float4 bv = *reinterpret_cast<const float4*>(&Bs[kk][tn]);
            acc[0][0] += a0 * bv.x; acc[0][1] += a0 * bv.y; acc[0][2] += a0 * bv.z; acc[0][3] += a0 * bv.w;
            acc[1][0] += a1 * bv.x; acc[1][1] += a1 * bv.y; acc[1][2] += a1 * bv.z; acc[1][3] += a1 * bv.w;
            acc[2][0] += a2 * bv.x; acc[2][1] += a2 * bv.y; acc[2][2] += a2 * bv.z; acc[2][3] += a2 * bv.w;
            acc[3][0] += a3 * bv.x; acc[3][1] += a3 * bv.y; acc[3][2] += a3 * bv.z; acc[3][3] += a3 * bv.w;
        }
        __syncthreads();
    }

#pragma unroll
    for (int i = 0; i < 4; ++i) {
        const int node = block0 + tm + i;
        if (node >= nN) continue;
#pragma unroll
        for (int j = 0; j < 4; ++j) {
            const int col = tn + j;
            if (col < NOUT)
                out[(size_t)node * NOUT + col] = acc[i][j] + bias[col];
        }
    }
}

// ----------------------------- launch ---------------------------------------

extern "C" void kernel_launch(void* const* d_in, const int* in_sizes, int n_in,
                              void* d_out, int out_size, void* d_ws, size_t ws_size,
                              hipStream_t stream) {
    const float* x    = (const float*)d_in[0];
    const int*   ei   = (const int*)d_in[1];
    const float* W1l  = (const float*)d_in[2];
    const float* b1   = (const float*)d_in[3];
    const float* W1r  = (const float*)d_in[4];
    const float* W2l  = (const float*)d_in[5];
    const float* b2   = (const float*)d_in[6];
    const float* W2r  = (const float*)d_in[7];
    const float* W3l  = (const float*)d_in[8];
    const float* b3   = (const float*)d_in[9];
    const float* W3r  = (const float*)d_in[10];
    const float* Wout = (const float*)d_in[11];
    const float* bout = (const float*)d_in[12];

    const int N = in_sizes[0] / 128;   // 100000
    const int E = in_sizes[1] / 2;     // 1600000
    const int* src  = ei;
    const int* dstA = ei + E;
    const int nbc = (N + 1023) >> 10;  // coarse buckets (<= MAXBC for this problem)

    char* ws = (char*)d_ws;
    size_t o = 0;
    int* bcur    = (int*)(ws + o); o += ws_align((size_t)MAXBC * 4);
    int* bbase   = (int*)(ws + o); o += ws_align((size_t)MAXBC * 4);
    int* rowptr  = (int*)(ws + o); o += ws_align((size_t)(N + 1) * 4);
    int* csr     = (int*)(ws + o); o += ws_align((size_t)E * 4);
    unsigned* ebuf = (unsigned*)(ws + o); o += ws_align((size_t)MAXBC * EB_CAP * 4);
    unsigned short* xl  = (unsigned short*)(ws + o); o += ws_align((size_t)N * 64 * 2);
    float*          xr  = (float*)(ws + o);          o += ws_align((size_t)N * 64 * 4);
    unsigned short* hAb = (unsigned short*)(ws + o); o += ws_align((size_t)N * 64 * 2);
    unsigned short* hBb = (unsigned short*)(ws + o); o += ws_align((size_t)N * 64 * 2);
    unsigned short* h3b = (unsigned short*)(ws + o); o += ws_align((size_t)N * 64 * 2);
    float* outp = (float*)d_out;

    const int projGrid = (N + 127) / 128;
    const int gatherGrid = (N + 3) / 4;
    const int headGrid = (N + 63) / 64;

    // ---- CSR build (LDS-staged binning) ----
    zero_kernel<<<1, 256, 0, stream>>>(bcur, MAXBC);
    pass1_bin<<<(E + 4095) / 4096, 256, 0, stream>>>(src, dstA, bcur, ebuf, E, N, nbc);
    scan_buckets<<<1, 256, 0, stream>>>(bcur, bbase, nbc);
    pass2_build<<<nbc, 256, 0, stream>>>(ebuf, bcur, bbase, rowptr, csr, N, nbc);

    // ---- layer 1 (128 -> 64, ELU) ----
    proj2_mfma<128, true><<<projGrid, 256, 0, stream>>>(x, W1l, W1r, b1, xl, xr, N);
    gather_kernel<true><<<gatherGrid, 256, 0, stream>>>(xl, xr, rowptr, csr, hAb, N, E);

    // ---- layer 2 (64 -> 64, ELU) ----
    proj2_mfma<64, false><<<projGrid, 256, 0, stream>>>(hAb, W2l, W2r, b2, xl, xr, N);
    gather_kernel<true><<<gatherGrid, 256, 0, stream>>>(xl, xr, rowptr, csr, hBb, N, E);

    // ---- layer 3 (64 -> 64, no ELU) ----
    proj2_mfma<64, false><<<projGrid, 256, 0, stream>>>(hBb, W3l, W3r, b3, xl, xr, N);
    gather_kernel<false><<<gatherGrid, 256, 0, stream>>>(xl, xr, rowptr, csr, h3b, N, E);

    // ---- head (64 -> 40, fp32 math, bf16 input) ----
    head_kernel<64, 40><<<headGrid, 256, 0, stream>>>(h3b, Wout, bout, outp, N);
}

// Round 8
// 328.848 us; speedup vs baseline: 17.2914x; 1.1497x over previous
//
#include <hip/hip_runtime.h>

// ---------------------------------------------------------------------------
// SAGEConvNet round 7: gather v3 — 16-deep independent row loads per wave
// (MLP/latency attack). lane = feature (2B); batch of 16 edges: load idx[16],
// issue 16 independent xl-row loads, then reduce. CSR build + MFMA projections
// unchanged from R6.
// ---------------------------------------------------------------------------

static inline size_t ws_align(size_t x) { return (x + 511) & ~size_t(511); }

#define MAXBC  104     // max coarse buckets supported (N <= 104*1024)
#define CAPL   96      // LDS slots per bucket per block (avg fill ~42)
#define EB_CAP 24576   // ebuf region capacity per bucket (mean 16384, +64 sigma)

using frag_ab = __attribute__((ext_vector_type(8))) short;   // 8 bf16
using f32x4   = __attribute__((ext_vector_type(4))) float;   // 4 fp32 acc
using us4     = __attribute__((ext_vector_type(4))) unsigned short;

__device__ inline short f2bf(float f) {            // RNE fp32 -> bf16
    unsigned u = __builtin_bit_cast(unsigned, f);
    u += 0x7fff + ((u >> 16) & 1);
    return (short)(u >> 16);
}
__device__ inline float b2f(unsigned short h) {
    unsigned u = ((unsigned)h) << 16;
    return __builtin_bit_cast(float, u);
}

// ----------------------------- utility --------------------------------------

__global__ void zero_kernel(int* __restrict__ p, int n) {
    int i = blockIdx.x * blockDim.x + threadIdx.x;
    if (i < n) p[i] = 0;
}

// ----------------------------- CSR build ------------------------------------

// Bin 4096 edges/block into LDS bucket buffers; bulk-flush per bucket.
__global__ void pass1_bin(const int* __restrict__ src, const int* __restrict__ dst,
                          int* __restrict__ bcur, unsigned* __restrict__ ebuf,
                          int nE, int nN, int nbc) {
    __shared__ unsigned lbuf[MAXBC][CAPL];
    __shared__ int bcnt[MAXBC];
    __shared__ int gbase[MAXBC];
    const int t = threadIdx.x;
    const int e0 = blockIdx.x * 4096;
    for (int i = t; i < MAXBC; i += 256) bcnt[i] = 0;
    __syncthreads();
#pragma unroll
    for (int q = 0; q < 16; ++q) {
        const int e = e0 + q * 256 + t;
        if (e < nE) {
            const unsigned d = (unsigned)dst[e];
            const unsigned s = (unsigned)src[e];
            if (d < (unsigned)nN && s < (unsigned)nN) {
                const int cb = (int)(d >> 10);
                const unsigned v = ((d & 1023u) << 17) | s;
                const int pos = atomicAdd(&bcnt[cb], 1);
                if (pos < CAPL) {
                    lbuf[cb][pos] = v;
                } else {
                    // rare overflow: direct global append (contained)
                    const int gp = atomicAdd(&bcur[cb], 1);
                    if (gp < EB_CAP) ebuf[(size_t)cb * EB_CAP + gp] = v;
                }
            }
        }
    }
    __syncthreads();
    // reserve contiguous global slots per bucket
    for (int b = t; b < nbc; b += 256) {
        const int cnt = min(bcnt[b], CAPL);
        bcnt[b] = cnt;
        gbase[b] = (cnt > 0) ? atomicAdd(&bcur[b], cnt) : 0;
    }
    __syncthreads();
    // cooperative coalesced flush: wave w handles buckets w, w+4, ...
    const int wid = t >> 6, lane = t & 63;
    for (int b = wid; b < nbc; b += 4) {
        const int cnt = bcnt[b];
        const int gb = gbase[b];
        for (int i = lane; i < cnt; i += 64) {
            const int gp = gb + i;
            if (gp < EB_CAP) ebuf[(size_t)b * EB_CAP + gp] = lbuf[b][i];
        }
    }
}

// exclusive scan of bucket counts (single block, nbc <= 256)
__global__ void scan_buckets(const int* __restrict__ bcur, int* __restrict__ bbase, int nbc) {
    __shared__ int sdata[256];
    const int t = threadIdx.x;
    const int v = (t < nbc) ? min(bcur[t], EB_CAP) : 0;
    sdata[t] = v;
    __syncthreads();
    for (int off = 1; off < 256; off <<= 1) {
        int add = (t >= off) ? sdata[t - off] : 0;
        __syncthreads();
        sdata[t] += add;
        __syncthreads();
    }
    if (t < nbc) bbase[t] = sdata[t] - v;   // exclusive
}

// per-bucket: histogram -> rowptr, then csr scatter into block-owned window.
__global__ void pass2_build(const unsigned* __restrict__ ebuf,
                            const int* __restrict__ bcur, const int* __restrict__ bbase,
                            int* __restrict__ rowptr, int* __restrict__ csr,
                            int nN, int nbc) {
    __shared__ int lcnt[1024];
    __shared__ int lcur[1024];
    __shared__ int sdata[256];
    const int b = blockIdx.x;
    const int node0 = b << 10;
    const int nloc = min(1024, nN - node0);
    if (nloc <= 0) return;
    const int cnt  = min(bcur[b], EB_CAP);
    const int base = bbase[b];
    const int t = threadIdx.x;
    const unsigned* eb = ebuf + (size_t)b * EB_CAP;

    for (int i = t; i < 1024; i += 256) lcnt[i] = 0;
    __syncthreads();
    for (int i = t; i < cnt; i += 256) atomicAdd(&lcnt[eb[i] >> 17], 1);
    __syncthreads();
    // exclusive scan of 1024 counts (256 threads x 4)
    int v[4];
    int tsum = 0;
#pragma unroll
    for (int q = 0; q < 4; ++q) { v[q] = lcnt[t * 4 + q]; tsum += v[q]; }
    sdata[t] = tsum;
    __syncthreads();
    for (int off = 1; off < 256; off <<= 1) {
        int add = (t >= off) ? sdata[t - off] : 0;
        __syncthreads();
        sdata[t] += add;
        __syncthreads();
    }
    int run = sdata[t] - tsum;
#pragma unroll
    for (int q = 0; q < 4; ++q) {
        const int l = t * 4 + q;
        lcur[l] = run;
        if (l < nloc) rowptr[node0 + l] = base + run;
        run += v[q];
    }
    if (b == nbc - 1 && t == 0) rowptr[nN] = base + cnt;
    __syncthreads();
    // scatter into the block-owned csr window (<=96KB contiguous; L2-merged)
    for (int i = t; i < cnt; i += 256) {
        const unsigned ev = eb[i];
        const int pos = atomicAdd(&lcur[ev >> 17], 1);
        csr[base + pos] = (int)(ev & 0x1FFFFu);
    }
}

// --------------------- dual projection via bf16 MFMA -------------------------
template<int F, bool AF32>
__global__ void proj2_mfma(const void* __restrict__ Aptr,
                           const float* __restrict__ Wl,
                           const float* __restrict__ Wr,
                           const float* __restrict__ bias,
                           unsigned short* __restrict__ xl,  // bf16 [N][64]
                           float* __restrict__ xr,           // fp32 [N][64]
                           int nN) {
    const int t    = threadIdx.x;
    const int wave = t >> 6;
    const int lane = t & 63;
    const int lg   = lane >> 4;   // k-group (0..3)
    const int lr   = lane & 15;   // row (A) / col (B,C)
    const int mbase = blockIdx.x * 128 + wave * 32;

    const float*          Af = (const float*)Aptr;
    const unsigned short* Ab = (const unsigned short*)Aptr;

    f32x4 accl[2][4] = {};
    f32x4 accr[2][4] = {};

#pragma unroll
    for (int ks = 0; ks < F / 32; ++ks) {
        const int k0 = ks * 32 + lg * 8;
        frag_ab afr[2];
#pragma unroll
        for (int mf = 0; mf < 2; ++mf) {
            int row = mbase + mf * 16 + lr;
            if (row >= nN) row = nN - 1;           // clamp; tail rows masked at store
            if constexpr (AF32) {
                const float4 f0 = *reinterpret_cast<const float4*>(Af + (size_t)row * F + k0);
                const float4 f1 = *reinterpret_cast<const float4*>(Af + (size_t)row * F + k0 + 4);
                frag_ab a;
                a[0] = f2bf(f0.x); a[1] = f2bf(f0.y); a[2] = f2bf(f0.z); a[3] = f2bf(f0.w);
                a[4] = f2bf(f1.x); a[5] = f2bf(f1.y); a[6] = f2bf(f1.z); a[7] = f2bf(f1.w);
                afr[mf] = a;
            } else {
                afr[mf] = *reinterpret_cast<const frag_ab*>(Ab + (size_t)row * F + k0);
            }
        }
#pragma unroll
        for (int nf = 0; nf < 4; ++nf) {
            const int col = nf * 16 + lr;
            const float4 l0 = *reinterpret_cast<const float4*>(Wl + (size_t)col * F + k0);
            const float4 l1 = *reinterpret_cast<const float4*>(Wl + (size_t)col * F + k0 + 4);
            const float4 r0 = *reinterpret_cast<const float4*>(Wr + (size_t)col * F + k0);
            const float4 r1 = *reinterpret_cast<const float4*>(Wr + (size_t)col * F + k0 + 4);
            frag_ab bl, br;
            bl[0] = f2bf(l0.x); bl[1] = f2bf(l0.y); bl[2] = f2bf(l0.z); bl[3] = f2bf(l0.w);
            bl[4] = f2bf(l1.x); bl[5] = f2bf(l1.y); bl[6] = f2bf(l1.z); bl[7] = f2bf(l1.w);
            br[0] = f2bf(r0.x); br[1] = f2bf(r0.y); br[2] = f2bf(r0.z); br[3] = f2bf(r0.w);
            br[4] = f2bf(r1.x); br[5] = f2bf(r1.y); br[6] = f2bf(r1.z); br[7] = f2bf(r1.w);
            accl[0][nf] = __builtin_amdgcn_mfma_f32_16x16x32_bf16(afr[0], bl, accl[0][nf], 0, 0, 0);
            accl[1][nf] = __builtin_amdgcn_mfma_f32_16x16x32_bf16(afr[1], bl, accl[1][nf], 0, 0, 0);
            accr[0][nf] = __builtin_amdgcn_mfma_f32_16x16x32_bf16(afr[0], br, accr[0][nf], 0, 0, 0);
            accr[1][nf] = __builtin_amdgcn_mfma_f32_16x16x32_bf16(afr[1], br, accr[1][nf], 0, 0, 0);
        }
    }

    // C/D layout: col=lane&15, row=(lane>>4)*4+reg   [m89-verified]
#pragma unroll
    for (int mf = 0; mf < 2; ++mf) {
#pragma unroll
        for (int nf = 0; nf < 4; ++nf) {
            const int col = nf * 16 + lr;
            const float bv = bias[col];
#pragma unroll
            for (int j = 0; j < 4; ++j) {
                const int row = mbase + mf * 16 + lg * 4 + j;
                if (row < nN) {
                    xl[(size_t)row * 64 + col] = (unsigned short)f2bf(accl[mf][nf][j]);
                    xr[(size_t)row * 64 + col] = accr[mf][nf][j] + bv;
                }
            }
        }
    }
}

// ----------------------------- gather-mean v3 --------------------------------
// one wave per node; lane = feature. Batches of 16 edges: stage 16 indices,
// issue 16 INDEPENDENT row loads (all in flight), then reduce. Tail uses a
// clamped batch (redundant loads hit the same cache line).
template<bool DOELU>
__global__ void gather_kernel(const unsigned short* __restrict__ xl,
                              const float* __restrict__ xr,
                              const int* __restrict__ rowptr, const int* __restrict__ csr,
                              unsigned short* __restrict__ outp, int nN, int nE) {
    const int node = blockIdx.x * (blockDim.x >> 6) + (threadIdx.x >> 6);
    if (node >= nN) return;
    const int lane = threadIdx.x & 63;
    int b = rowptr[node];
    int e = rowptr[node + 1];
    b = max(0, min(b, nE));
    e = max(b, min(e, nE));
    const float d = (float)(e - b);

    float acc = 0.f;
    int i = b;
    // full batches of 16 — no clamping
    for (; i + 16 <= e; i += 16) {
        int sv[16];
#pragma unroll
        for (int j = 0; j < 16; ++j) sv[j] = csr[i + j];
        unsigned short v[16];
#pragma unroll
        for (int j = 0; j < 16; ++j)
            v[j] = xl[(size_t)(unsigned)sv[j] * 64 + lane];
#pragma unroll
        for (int j = 0; j < 16; ++j) acc += b2f(v[j]);
    }
    // tail batch (clamped; e > i here when it runs)
    if (i < e) {
        const int lim = e - i;       // 1..15
        int sv[16];
#pragma unroll
        for (int j = 0; j < 16; ++j) sv[j] = csr[i + min(j, lim - 1)];
        unsigned short v[16];
#pragma unroll
        for (int j = 0; j < 16; ++j)
            v[j] = xl[(size_t)(unsigned)sv[j] * 64 + lane];
#pragma unroll
        for (int j = 0; j < 16; ++j) acc += (j < lim) ? b2f(v[j]) : 0.f;
    }

    float vout = acc / fmaxf(d, 1.0f) + xr[(size_t)node * 64 + lane];
    if (DOELU) vout = vout > 0.f ? vout : expm1f(vout);
    outp[(size_t)node * 64 + lane] = (unsigned short)f2bf(vout);
}

// ----------------------------- head (fp32 VALU, bf16 A) ----------------------
template<int F, int NOUT>
__global__ void head_kernel(const unsigned short* __restrict__ A,
                            const float* __restrict__ W,
                            const float* __restrict__ bias,
                            float* __restrict__ out, int nN) {
    constexpr int NCH = F / 32;
    __shared__ float As[64][36];
    __shared__ float Bs[32][64];

    const int t = threadIdx.x;
    const int block0 = blockIdx.x * 64;
    const int tm = (t >> 4) << 2;
    const int tn = (t & 15) << 2;

    float acc[4][4] = {};

    for (int ch = 0; ch < NCH; ++ch) {
        const int kg0 = ch * 32;
        {
            const int kk = (t & 7) * 4;
#pragma unroll
            for (int r = 0; r < 2; ++r) {
                const int n = (t >> 3) + r * 32;
                const int node = block0 + n;
                float4 v = make_float4(0.f, 0.f, 0.f, 0.f);
                if (node < nN) {
                    const us4 u = *reinterpret_cast<const us4*>(A + (size_t)node * F + kg0 + kk);
                    v.x = b2f(u[0]); v.y = b2f(u[1]); v.z = b2f(u[2]); v.w = b2f(u[3]);
                }
                *reinterpret_cast<float4*>(&As[n][kk]) = v;
            }
        }
        {
            const int j = t & 63;
#pragma unroll
            for (int p = 0; p < 8; ++p) {
                const int kk = (t >> 6) + p * 4;
                Bs[kk][j] = (j < NOUT) ? W[(size_t)j * F + kg0 + kk] : 0.0f;
            }
        }
        __syncthreads();
#pragma unroll
        for (int kk = 0; kk < 32; ++kk) {
            const float a0 = As[tm + 0][kk];
            const float a1 = As[tm + 1][kk];
            const float a2 = As[tm + 2][kk];
            const float a3 = As[tm + 3][kk];
            const float4 bv = *reinterpret_cast<const float4*>(&Bs[kk][tn]);
            acc[0][0] += a0 * bv.x; acc[0][1] += a0 * bv.y; acc[0][2] += a0 * bv.z; acc[0][3] += a0 * bv.w;
            acc[1][0] += a1 * bv.x; acc[1][1] += a1 * bv.y; acc[1][2] += a1 * bv.z; acc[1][3] += a1 * bv.w;
            acc[2][0] += a2 * bv.x; acc[2][1] += a2 * bv.y; acc[2][2] += a2 * bv.z; acc[2][3] += a2 * bv.w;
            acc[3][0] += a3 * bv.x; acc[3][1] += a3 * bv.y; acc[3][2] += a3 * bv.z; acc[3][3] += a3 * bv.w;
        }
        __syncthreads();
    }

#pragma unroll
    for (int i = 0; i < 4; ++i) {
        const int node = block0 + tm + i;
        if (node >= nN) continue;
#pragma unroll
        for (int j = 0; j < 4; ++j) {
            const int col = tn + j;
            if (col < NOUT)
                out[(size_t)node * NOUT + col] = acc[i][j] + bias[col];
        }
    }
}

// ----------------------------- launch ---------------------------------------

extern "C" void kernel_launch(void* const* d_in, const int* in_sizes, int n_in,
                              void* d_out, int out_size, void* d_ws, size_t ws_size,
                              hipStream_t stream) {
    const float* x    = (const float*)d_in[0];
    const int*   ei   = (const int*)d_in[1];
    const float* W1l  = (const float*)d_in[2];
    const float* b1   = (const float*)d_in[3];
    const float* W1r  = (const float*)d_in[4];
    const float* W2l  = (const float*)d_in[5];
    const float* b2   = (const float*)d_in[6];
    const float* W2r  = (const float*)d_in[7];
    const float* W3l  = (const float*)d_in[8];
    const float* b3   = (const float*)d_in[9];
    const float* W3r  = (const float*)d_in[10];
    const float* Wout = (const float*)d_in[11];
    const float* bout = (const float*)d_in[12];

    const int N = in_sizes[0] / 128;   // 100000
    const int E = in_sizes[1] / 2;     // 1600000
    const int* src  = ei;
    const int* dstA = ei + E;
    const int nbc = (N + 1023) >> 10;  // coarse buckets (<= MAXBC for this problem)

    char* ws = (char*)d_ws;
    size_t o = 0;
    int* bcur    = (int*)(ws + o); o += ws_align((size_t)MAXBC * 4);
    int* bbase   = (int*)(ws + o); o += ws_align((size_t)MAXBC * 4);
    int* rowptr  = (int*)(ws + o); o += ws_align((size_t)(N + 1) * 4);
    int* csr     = (int*)(ws + o); o += ws_align((size_t)E * 4);
    unsigned* ebuf = (unsigned*)(ws + o); o += ws_align((size_t)MAXBC * EB_CAP * 4);
    unsigned short* xl  = (unsigned short*)(ws + o); o += ws_align((size_t)N * 64 * 2);
    float*          xr  = (float*)(ws + o);          o += ws_align((size_t)N * 64 * 4);
    unsigned short* hAb = (unsigned short*)(ws + o); o += ws_align((size_t)N * 64 * 2);
    unsigned short* hBb = (unsigned short*)(ws + o); o += ws_align((size_t)N * 64 * 2);
    unsigned short* h3b = (unsigned short*)(ws + o); o += ws_align((size_t)N * 64 * 2);
    float* outp = (float*)d_out;

    const int projGrid = (N + 127) / 128;
    const int gatherGrid = (N + 3) / 4;
    const int headGrid = (N + 63) / 64;

    // ---- CSR build (LDS-staged binning) ----
    zero_kernel<<<1, 256, 0, stream>>>(bcur, MAXBC);
    pass1_bin<<<(E + 4095) / 4096, 256, 0, stream>>>(src, dstA, bcur, ebuf, E, N, nbc);
    scan_buckets<<<1, 256, 0, stream>>>(bcur, bbase, nbc);
    pass2_build<<<nbc, 256, 0, stream>>>(ebuf, bcur, bbase, rowptr, csr, N, nbc);

    // ---- layer 1 (128 -> 64, ELU) ----
    proj2_mfma<128, true><<<projGrid, 256, 0, stream>>>(x, W1l, W1r, b1, xl, xr, N);
    gather_kernel<true><<<gatherGrid, 256, 0, stream>>>(xl, xr, rowptr, csr, hAb, N, E);

    // ---- layer 2 (64 -> 64, ELU) ----
    proj2_mfma<64, false><<<projGrid, 256, 0, stream>>>(hAb, W2l, W2r, b2, xl, xr, N);
    gather_kernel<true><<<gatherGrid, 256, 0, stream>>>(xl, xr, rowptr, csr, hBb, N, E);

    // ---- layer 3 (64 -> 64, no ELU) ----
    proj2_mfma<64, false><<<projGrid, 256, 0, stream>>>(hBb, W3l, W3r, b3, xl, xr, N);
    gather_kernel<false><<<gatherGrid, 256, 0, stream>>>(xl, xr, rowptr, csr, h3b, N, E);

    // ---- head (64 -> 40, fp32 math, bf16 input) ----
    head_kernel<64, 40><<<headGrid, 256, 0, stream>>>(h3b, Wout, bout, outp, N);
}

// Round 9
// 276.838 us; speedup vs baseline: 20.5399x; 1.1879x over previous
//
#include <hip/hip_runtime.h>

// ---------------------------------------------------------------------------
// SAGEConvNet round 8:
//   - prep_all: one-shot W -> bf16 in MFMA B-frag layout (fw[oct][col][8])
//   - proj2_mfma v2: B-frag = single b128 L2-hot load; 16 rows/wave (2x waves)
//   - gather v4: shfl-broadcast csr indices + 32-bit row offsets
// CSR build (LDS-binned) unchanged from R5.
// ---------------------------------------------------------------------------

static inline size_t ws_align(size_t x) { return (x + 511) & ~size_t(511); }

#define MAXBC  104     // max coarse buckets supported (N <= 104*1024)
#define CAPL   96      // LDS slots per bucket per block (avg fill ~42)
#define EB_CAP 24576   // ebuf region capacity per bucket

using frag_ab = __attribute__((ext_vector_type(8))) short;   // 8 bf16
using f32x4   = __attribute__((ext_vector_type(4))) float;   // 4 fp32 acc
using us4     = __attribute__((ext_vector_type(4))) unsigned short;

__device__ inline short f2bf(float f) {            // RNE fp32 -> bf16
    unsigned u = __builtin_bit_cast(unsigned, f);
    u += 0x7fff + ((u >> 16) & 1);
    return (short)(u >> 16);
}
__device__ inline float b2f(unsigned short h) {
    unsigned u = ((unsigned)h) << 16;
    return __builtin_bit_cast(float, u);
}

// ----------------------------- utility --------------------------------------

__global__ void zero_kernel(int* __restrict__ p, int n) {
    int i = blockIdx.x * blockDim.x + threadIdx.x;
    if (i < n) p[i] = 0;
}

// W -> bf16 B-frag layout. Per matrix (64 cols x F): fw[k>>3][col][k&7].
// fw arena: [0,8192)=W1l, [8192,16384)=W1r, then 4096 each: W2l,W2r,W3l,W3r.
__global__ void prep_all(const float* __restrict__ W1l, const float* __restrict__ W1r,
                         const float* __restrict__ W2l, const float* __restrict__ W2r,
                         const float* __restrict__ W3l, const float* __restrict__ W3r,
                         unsigned short* __restrict__ fw) {
    const int idx = blockIdx.x * 256 + threadIdx.x;   // 0..32767
    if (idx >= 32768) return;
    const float* W;
    unsigned short* out;
    int F, rel;
    if (idx < 8192)       { W = W1l; out = fw;        F = 128; rel = idx; }
    else if (idx < 16384) { W = W1r; out = fw + 8192; F = 128; rel = idx - 8192; }
    else {
        const int q = (idx - 16384) >> 12;
        rel = (idx - 16384) & 4095;
        F = 64;
        W = (q == 0) ? W2l : (q == 1) ? W2r : (q == 2) ? W3l : W3r;
        out = fw + 16384 + q * 4096;
    }
    const int k = rel % F;                // rel = col*F + k
    const int col = rel / F;
    out[(k >> 3) * 512 + col * 8 + (k & 7)] = (unsigned short)f2bf(W[rel]);
}

// ----------------------------- CSR build ------------------------------------

__global__ void pass1_bin(const int* __restrict__ src, const int* __restrict__ dst,
                          int* __restrict__ bcur, unsigned* __restrict__ ebuf,
                          int nE, int nN, int nbc) {
    __shared__ unsigned lbuf[MAXBC][CAPL];
    __shared__ int bcnt[MAXBC];
    __shared__ int gbase[MAXBC];
    const int t = threadIdx.x;
    const int e0 = blockIdx.x * 4096;
    for (int i = t; i < MAXBC; i += 256) bcnt[i] = 0;
    __syncthreads();
#pragma unroll
    for (int q = 0; q < 16; ++q) {
        const int e = e0 + q * 256 + t;
        if (e < nE) {
            const unsigned d = (unsigned)dst[e];
            const unsigned s = (unsigned)src[e];
            if (d < (unsigned)nN && s < (unsigned)nN) {
                const int cb = (int)(d >> 10);
                const unsigned v = ((d & 1023u) << 17) | s;
                const int pos = atomicAdd(&bcnt[cb], 1);
                if (pos < CAPL) {
                    lbuf[cb][pos] = v;
                } else {
                    const int gp = atomicAdd(&bcur[cb], 1);
                    if (gp < EB_CAP) ebuf[(size_t)cb * EB_CAP + gp] = v;
                }
            }
        }
    }
    __syncthreads();
    for (int b = t; b < nbc; b += 256) {
        const int cnt = min(bcnt[b], CAPL);
        bcnt[b] = cnt;
        gbase[b] = (cnt > 0) ? atomicAdd(&bcur[b], cnt) : 0;
    }
    __syncthreads();
    const int wid = t >> 6, lane = t & 63;
    for (int b = wid; b < nbc; b += 4) {
        const int cnt = bcnt[b];
        const int gb = gbase[b];
        for (int i = lane; i < cnt; i += 64) {
            const int gp = gb + i;
            if (gp < EB_CAP) ebuf[(size_t)b * EB_CAP + gp] = lbuf[b][i];
        }
    }
}

__global__ void scan_buckets(const int* __restrict__ bcur, int* __restrict__ bbase, int nbc) {
    __shared__ int sdata[256];
    const int t = threadIdx.x;
    const int v = (t < nbc) ? min(bcur[t], EB_CAP) : 0;
    sdata[t] = v;
    __syncthreads();
    for (int off = 1; off < 256; off <<= 1) {
        int add = (t >= off) ? sdata[t - off] : 0;
        __syncthreads();
        sdata[t] += add;
        __syncthreads();
    }
    if (t < nbc) bbase[t] = sdata[t] - v;   // exclusive
}

__global__ void pass2_build(const unsigned* __restrict__ ebuf,
                            const int* __restrict__ bcur, const int* __restrict__ bbase,
                            int* __restrict__ rowptr, int* __restrict__ csr,
                            int nN, int nbc) {
    __shared__ int lcnt[1024];
    __shared__ int lcur[1024];
    __shared__ int sdata[256];
    const int b = blockIdx.x;
    const int node0 = b << 10;
    const int nloc = min(1024, nN - node0);
    if (nloc <= 0) return;
    const int cnt  = min(bcur[b], EB_CAP);
    const int base = bbase[b];
    const int t = threadIdx.x;
    const unsigned* eb = ebuf + (size_t)b * EB_CAP;

    for (int i = t; i < 1024; i += 256) lcnt[i] = 0;
    __syncthreads();
    for (int i = t; i < cnt; i += 256) atomicAdd(&lcnt[eb[i] >> 17], 1);
    __syncthreads();
    int v[4];
    int tsum = 0;
#pragma unroll
    for (int q = 0; q < 4; ++q) { v[q] = lcnt[t * 4 + q]; tsum += v[q]; }
    sdata[t] = tsum;
    __syncthreads();
    for (int off = 1; off < 256; off <<= 1) {
        int add = (t >= off) ? sdata[t - off] : 0;
        __syncthreads();
        sdata[t] += add;
        __syncthreads();
    }
    int run = sdata[t] - tsum;
#pragma unroll
    for (int q = 0; q < 4; ++q) {
        const int l = t * 4 + q;
        lcur[l] = run;
        if (l < nloc) rowptr[node0 + l] = base + run;
        run += v[q];
    }
    if (b == nbc - 1 && t == 0) rowptr[nN] = base + cnt;
    __syncthreads();
    for (int i = t; i < cnt; i += 256) {
        const unsigned ev = eb[i];
        const int pos = atomicAdd(&lcur[ev >> 17], 1);
        csr[base + pos] = (int)(ev & 0x1FFFFu);
    }
}

// --------------------- dual projection via bf16 MFMA v2 ----------------------
// 16 rows per wave (1 m-frag), 4 waves/block -> 64 rows/block.
// B-frags: single b128 load from pre-converted fw (L2-hot).
template<int F, bool AF32>
__global__ void proj2_mfma(const void* __restrict__ Aptr,
                           const unsigned short* __restrict__ fwl,
                           const unsigned short* __restrict__ fwr,
                           const float* __restrict__ bias,
                           unsigned short* __restrict__ xl,  // bf16 [N][64]
                           float* __restrict__ xr,           // fp32 [N][64]
                           int nN) {
    const int t    = threadIdx.x;
    const int wave = t >> 6;
    const int lane = t & 63;
    const int lg   = lane >> 4;   // k-group (0..3)
    const int lr   = lane & 15;   // row (A) / col (B,C)
    const int row0 = blockIdx.x * 64 + wave * 16;

    const float*          Af = (const float*)Aptr;
    const unsigned short* Ab = (const unsigned short*)Aptr;

    f32x4 accl[4] = {};
    f32x4 accr[4] = {};

#pragma unroll
    for (int ks = 0; ks < F / 32; ++ks) {
        const int k0 = ks * 32 + lg * 8;
        frag_ab afr;
        {
            int row = row0 + lr;
            if (row >= nN) row = nN - 1;           // clamp; tail masked at store
            if constexpr (AF32) {
                const float4 f0 = *reinterpret_cast<const float4*>(Af + (size_t)row * F + k0);
                const float4 f1 = *reinterpret_cast<const float4*>(Af + (size_t)row * F + k0 + 4);
                afr[0] = f2bf(f0.x); afr[1] = f2bf(f0.y); afr[2] = f2bf(f0.z); afr[3] = f2bf(f0.w);
                afr[4] = f2bf(f1.x); afr[5] = f2bf(f1.y); afr[6] = f2bf(f1.z); afr[7] = f2bf(f1.w);
            } else {
                afr = *reinterpret_cast<const frag_ab*>(Ab + (size_t)row * F + k0);
            }
        }
        const int ob = (ks * 4 + lg) * 512;   // octet base in fw (64 cols x 8)
#pragma unroll
        for (int nf = 0; nf < 4; ++nf) {
            const int col = nf * 16 + lr;
            const frag_ab bl = *reinterpret_cast<const frag_ab*>(fwl + ob + col * 8);
            const frag_ab br = *reinterpret_cast<const frag_ab*>(fwr + ob + col * 8);
            accl[nf] = __builtin_amdgcn_mfma_f32_16x16x32_bf16(afr, bl, accl[nf], 0, 0, 0);
            accr[nf] = __builtin_amdgcn_mfma_f32_16x16x32_bf16(afr, br, accr[nf], 0, 0, 0);
        }
    }

    // C/D layout: col=lane&15, row=(lane>>4)*4+reg   [m89-verified]
#pragma unroll
    for (int nf = 0; nf < 4; ++nf) {
        const int col = nf * 16 + lr;
        const float bv = bias[col];
#pragma unroll
        for (int j = 0; j < 4; ++j) {
            const int row = row0 + lg * 4 + j;
            if (row < nN) {
                xl[(size_t)row * 64 + col] = (unsigned short)f2bf(accl[nf][j]);
                xr[(size_t)row * 64 + col] = accr[nf][j] + bv;
            }
        }
    }
}

// ----------------------------- gather-mean v4 --------------------------------
// one wave per node; lane = feature. 16-edge batches: lanes 0-15 load the 16
// csr indices in ONE vector load, broadcast via shfl; 16 independent row loads
// with 32-bit byte offsets (SGPR base + voffset).
template<bool DOELU>
__global__ void gather_kernel(const unsigned short* __restrict__ xl,
                              const float* __restrict__ xr,
                              const int* __restrict__ rowptr, const int* __restrict__ csr,
                              unsigned short* __restrict__ outp, int nN, int nE) {
    const int node = blockIdx.x * (blockDim.x >> 6) + (threadIdx.x >> 6);
    if (node >= nN) return;
    const int lane = threadIdx.x & 63;
    const unsigned loff = (unsigned)(lane << 1);
    int b = rowptr[node];
    int e = rowptr[node + 1];
    b = max(0, min(b, nE));
    e = max(b, min(e, nE));
    const float d = (float)(e - b);
    const char* xlb = (const char*)xl;

    float acc = 0.f;
    int i = b;
    // full batches of 16
    for (; i + 16 <= e; i += 16) {
        const int iv = csr[i + (lane & 15)];
        unsigned short v[16];
#pragma unroll
        for (int j = 0; j < 16; ++j) {
            const unsigned s = (unsigned)__shfl(iv, j);
            v[j] = *(const unsigned short*)(xlb + (s * 128u + loff));
        }
#pragma unroll
        for (int j = 0; j < 16; ++j) acc += b2f(v[j]);
    }
    // tail batch (clamped loads, predicated adds)
    if (i < e) {
        const int lim = e - i;       // 1..15
        const int iv = csr[i + min(lane & 15, lim - 1)];
        unsigned short v[16];
#pragma unroll
        for (int j = 0; j < 16; ++j) {
            const unsigned s = (unsigned)__shfl(iv, j);
            v[j] = *(const unsigned short*)(xlb + (s * 128u + loff));
        }
#pragma unroll
        for (int j = 0; j < 16; ++j) acc += (j < lim) ? b2f(v[j]) : 0.f;
    }

    float vout = acc / fmaxf(d, 1.0f) + xr[(size_t)node * 64 + lane];
    if (DOELU) vout = vout > 0.f ? vout : expm1f(vout);
    outp[(size_t)node * 64 + lane] = (unsigned short)f2bf(vout);
}

// ----------------------------- head (fp32 VALU, bf16 A) ----------------------
template<int F, int NOUT>
__global__ void head_kernel(const unsigned short* __restrict__ A,
                            const float* __restrict__ W,
                            const float* __restrict__ bias,
                            float* __restrict__ out, int nN) {
    constexpr int NCH = F / 32;
    __shared__ float As[64][36];
    __shared__ float Bs[32][64];

    const int t = threadIdx.x;
    const int block0 = blockIdx.x * 64;
    const int tm = (t >> 4) << 2;
    const int tn = (t & 15) << 2;

    float acc[4][4] = {};

    for (int ch = 0; ch < NCH; ++ch) {
        const int kg0 = ch * 32;
        {
            const int kk = (t & 7) * 4;
#pragma unroll
            for (int r = 0; r < 2; ++r) {
                const int n = (t >> 3) + r * 32;
                const int node = block0 + n;
                float4 v = make_float4(0.f, 0.f, 0.f, 0.f);
                if (node < nN) {
                    const us4 u = *reinterpret_cast<const us4*>(A + (size_t)node * F + kg0 + kk);
                    v.x = b2f(u[0]); v.y = b2f(u[1]); v.z = b2f(u[2]); v.w = b2f(u[3]);
                }
                *reinterpret_cast<float4*>(&As[n][kk]) = v;
            }
        }
        {
            const int j = t & 63;
#pragma unroll
            for (int p = 0; p < 8; ++p) {
                const int kk = (t >> 6) + p * 4;
                Bs[kk][j] = (j < NOUT) ? W[(size_t)j * F + kg0 + kk] : 0.0f;
            }
        }
        __syncthreads();
#pragma unroll
        for (int kk = 0; kk < 32; ++kk) {
            const float a0 = As[tm + 0][kk];
            const float a1 = As[tm + 1][kk];
            const float a2 = As[tm + 2][kk];
            const float a3 = As[tm + 3][kk];
            const float4 bv = *reinterpret_cast<const float4*>(&Bs[kk][tn]);
            acc[0][0] += a0 * bv.x; acc[0][1] += a0 * bv.y; acc[0][2] += a0 * bv.z; acc[0][3] += a0 * bv.w;
            acc[1][0] += a1 * bv.x; acc[1][1] += a1 * bv.y; acc[1][2] += a1 * bv.z; acc[1][3] += a1 * bv.w;
            acc[2][0] += a2 * bv.x; acc[2][1] += a2 * bv.y; acc[2][2] += a2 * bv.z; acc[2][3] += a2 * bv.w;
            acc[3][0] += a3 * bv.x; acc[3][1] += a3 * bv.y; acc[3][2] += a3 * bv.z; acc[3][3] += a3 * bv.w;
        }
        __syncthreads();
    }

#pragma unroll
    for (int i = 0; i < 4; ++i) {
        const int node = block0 + tm + i;
        if (node >= nN) continue;
#pragma unroll
        for (int j = 0; j < 4; ++j) {
            const int col = tn + j;
            if (col < NOUT)
                out[(size_t)node * NOUT + col] = acc[i][j] + bias[col];
        }
    }
}

// ----------------------------- launch ---------------------------------------

extern "C" void kernel_launch(void* const* d_in, const int* in_sizes, int n_in,
                              void* d_out, int out_size, void* d_ws, size_t ws_size,
                              hipStream_t stream) {
    const float* x    = (const float*)d_in[0];
    const int*   ei   = (const int*)d_in[1];
    const float* W1l  = (const float*)d_in[2];
    const float* b1   = (const float*)d_in[3];
    const float* W1r  = (const float*)d_in[4];
    const float* W2l  = (const float*)d_in[5];
    const float* b2   = (const float*)d_in[6];
    const float* W2r  = (const float*)d_in[7];
    const float* W3l  = (const float*)d_in[8];
    const float* b3   = (const float*)d_in[9];
    const float* W3r  = (const float*)d_in[10];
    const float* Wout = (const float*)d_in[11];
    const float* bout = (const float*)d_in[12];

    const int N = in_sizes[0] / 128;   // 100000
    const int E = in_sizes[1] / 2;     // 1600000
    const int* src  = ei;
    const int* dstA = ei + E;
    const int nbc = (N + 1023) >> 10;

    char* ws = (char*)d_ws;
    size_t o = 0;
    int* bcur    = (int*)(ws + o); o += ws_align((size_t)MAXBC * 4);
    int* bbase   = (int*)(ws + o); o += ws_align((size_t)MAXBC * 4);
    int* rowptr  = (int*)(ws + o); o += ws_align((size_t)(N + 1) * 4);
    int* csr     = (int*)(ws + o); o += ws_align((size_t)E * 4);
    unsigned* ebuf = (unsigned*)(ws + o); o += ws_align((size_t)MAXBC * EB_CAP * 4);
    unsigned short* fw  = (unsigned short*)(ws + o); o += ws_align((size_t)32768 * 2);
    unsigned short* xl  = (unsigned short*)(ws + o); o += ws_align((size_t)N * 64 * 2);
    float*          xr  = (float*)(ws + o);          o += ws_align((size_t)N * 64 * 4);
    unsigned short* hAb = (unsigned short*)(ws + o); o += ws_align((size_t)N * 64 * 2);
    unsigned short* hBb = (unsigned short*)(ws + o); o += ws_align((size_t)N * 64 * 2);
    unsigned short* h3b = (unsigned short*)(ws + o); o += ws_align((size_t)N * 64 * 2);
    float* outp = (float*)d_out;

    const int projGrid = (N + 63) / 64;
    const int gatherGrid = (N + 3) / 4;
    const int headGrid = (N + 63) / 64;

    // ---- weight prep + CSR build ----
    zero_kernel<<<1, 256, 0, stream>>>(bcur, MAXBC);
    prep_all<<<128, 256, 0, stream>>>(W1l, W1r, W2l, W2r, W3l, W3r, fw);
    pass1_bin<<<(E + 4095) / 4096, 256, 0, stream>>>(src, dstA, bcur, ebuf, E, N, nbc);
    scan_buckets<<<1, 256, 0, stream>>>(bcur, bbase, nbc);
    pass2_build<<<nbc, 256, 0, stream>>>(ebuf, bcur, bbase, rowptr, csr, N, nbc);

    const unsigned short* fw1l = fw;
    const unsigned short* fw1r = fw + 8192;
    const unsigned short* fw2l = fw + 16384;
    const unsigned short* fw2r = fw + 16384 + 4096;
    const unsigned short* fw3l = fw + 16384 + 8192;
    const unsigned short* fw3r = fw + 16384 + 12288;

    // ---- layer 1 (128 -> 64, ELU) ----
    proj2_mfma<128, true><<<projGrid, 256, 0, stream>>>(x, fw1l, fw1r, b1, xl, xr, N);
    gather_kernel<true><<<gatherGrid, 256, 0, stream>>>(xl, xr, rowptr, csr, hAb, N, E);

    // ---- layer 2 (64 -> 64, ELU) ----
    proj2_mfma<64, false><<<projGrid, 256, 0, stream>>>(hAb, fw2l, fw2r, b2, xl, xr, N);
    gather_kernel<true><<<gatherGrid, 256, 0, stream>>>(xl, xr, rowptr, csr, hBb, N, E);

    // ---- layer 3 (64 -> 64, no ELU) ----
    proj2_mfma<64, false><<<projGrid, 256, 0, stream>>>(hBb, fw3l, fw3r, b3, xl, xr, N);
    gather_kernel<false><<<gatherGrid, 256, 0, stream>>>(xl, xr, rowptr, csr, h3b, N, E);

    // ---- head (64 -> 40, fp32 math, bf16 input) ----
    head_kernel<64, 40><<<headGrid, 256, 0, stream>>>(h3b, Wout, bout, outp, N);
}